// Round 5
// baseline (902.769 us; speedup 1.0000x reference)
//
#include <hip/hip_runtime.h>
#include <hip/hip_bf16.h>
#include <math.h>

#define WB 4
#define WS 2048
#define WD 512
#define WHID 64
#define NLAYER 6

typedef __attribute__((ext_vector_type(8))) short short8;
typedef __attribute__((ext_vector_type(4))) short short4v;
typedef __attribute__((ext_vector_type(4))) float floatx4;

__device__ __forceinline__ short f2bf(float f) {
    union { float f; unsigned u; } x; x.f = f;
    unsigned r = (x.u + 0x7fffu + ((x.u >> 16) & 1u)) >> 16;
    return (short)r;
}

__device__ __forceinline__ void gl_lds16(const short* g, short* l) {
    __builtin_amdgcn_global_load_lds(
        (const __attribute__((address_space(1))) unsigned*)g,
        (__attribute__((address_space(3))) unsigned*)l, 16, 0, 0);
}

__device__ __forceinline__ float block_reduce(float v, bool is_max) {
    __shared__ float tmp[4];
    int lane = threadIdx.x & 63, w = threadIdx.x >> 6;
#pragma unroll
    for (int off = 32; off; off >>= 1) {
        float o = __shfl_xor(v, off);
        v = is_max ? fmaxf(v, o) : v + o;
    }
    __syncthreads();
    if (lane == 0) tmp[w] = v;
    __syncthreads();
    int nw = blockDim.x >> 6;
    float r = tmp[0];
    for (int i = 1; i < nw; i++) r = is_max ? fmaxf(r, tmp[i]) : r + tmp[i];
    return r;
}

// ---------- 128x128 NT GEMM, 8 waves, BK=64, 3-buffer counted-vmcnt pipeline ----------
// A: [M][K] bf16 row-major, B: [N][K] bf16 row-major. K % 64 == 0.
// LDS layout: row r, 16B-block b holds global block (b ^ (r&7))  (linear dest for
// global_load_lds; swizzle realized by inverse-permuted per-lane GLOBAL source).
// EPI: 0 = bf16 ((acc+bias)*scale); 1 = bf16 transposed into vt[B][D][S] (+bias);
//      5 = f32 (+bias); 6 = QK: bf16 exp(acc) + row-sum partials into Lp;
//      7 = PV: bf16 acc * (scale / l[row]) with l reduced from Lp.
template<int EPI>
__global__ __launch_bounds__(512) void gemm8_k(
    const short* __restrict__ A, const short* __restrict__ Bm,
    const float* __restrict__ bias, float* __restrict__ Cf, short* __restrict__ Cb,
    int K, int lda, int ldb, int ldc,
    long sA, long sB, long sC, float scale, int b0, float* __restrict__ Lp)
{
    __shared__ __align__(16) short As[3][128 * 64];
    __shared__ __align__(16) short Bs[3][128 * 64];
    __shared__ float lds_l[128];
    int tid = threadIdx.x;
    int bz = b0 + blockIdx.z;
    int m0 = blockIdx.y * 128, n0 = blockIdx.x * 128;
    const short* Ab = A + (long)bz * sA + (long)m0 * lda;
    const short* Bb = Bm + (long)bz * sB + (long)n0 * ldb;
    long coff = (long)bz * sC;

    if (EPI == 7 && tid < 128) {
        float s = 0.f;
        const float* lp = Lp + (long)bz * 64 * WS + m0 + tid;
#pragma unroll 8
        for (int p2 = 0; p2 < 64; p2++) s += lp[(long)p2 * WS];
        lds_l[tid] = scale / s;
    }

    int lane = tid & 63, w = tid >> 6;
    int wm = (w >> 2) * 64, wn = (w & 3) * 32;

    floatx4 acc[4][2];
#pragma unroll
    for (int mi = 0; mi < 4; mi++)
#pragma unroll
        for (int ni = 0; ni < 2; ni++) acc[mi][ni] = (floatx4){0.f, 0.f, 0.f, 0.f};

    // staging: thread covers chunks tid and tid+512 (rows r0 and r0+64, same block)
    int r0 = tid >> 3;
    int sblk = (tid & 7) ^ (r0 & 7);
    const short* ga0 = Ab + (long)r0 * lda + sblk * 8;
    const short* gb0 = Bb + (long)r0 * ldb + sblk * 8;
    long lda64 = (long)64 * lda, ldb64 = (long)64 * ldb;

    // fragment read offsets (swizzled)
    int arow = wm + (lane & 15);
    int brow = wn + (lane & 15);
    int a7 = arow & 7, b7 = brow & 7;
    int kb = lane >> 4;  // 0..3
    int aoff0 = arow * 64 + ((kb ^ a7) * 8);
    int aoff1 = arow * 64 + (((kb + 4) ^ a7) * 8);
    int boff0 = brow * 64 + ((kb ^ b7) * 8);
    int boff1 = brow * 64 + (((kb + 4) ^ b7) * 8);

    int nt = K >> 6;

    auto stage = [&](int t, int b) {
        const short* ga = ga0 + t * 64;
        const short* gb = gb0 + t * 64;
        gl_lds16(ga, &As[b][tid * 8]);
        gl_lds16(ga + lda64, &As[b][(tid + 512) * 8]);
        gl_lds16(gb, &Bs[b][tid * 8]);
        gl_lds16(gb + ldb64, &Bs[b][(tid + 512) * 8]);
    };

    stage(0, 0);
    if (nt > 1) stage(1, 1);

    for (int t = 0; t < nt; t++) {
        int cur = t % 3;
        if (t + 2 < nt) {
            stage(t + 2, (t + 2) % 3);
            asm volatile("s_waitcnt vmcnt(8)" ::: "memory");
        } else if (t + 1 < nt) {
            asm volatile("s_waitcnt vmcnt(4)" ::: "memory");
        } else {
            asm volatile("s_waitcnt vmcnt(0)" ::: "memory");
        }
        __builtin_amdgcn_s_barrier();
        __builtin_amdgcn_sched_barrier(0);
        const short* as = As[cur];
        const short* bs = Bs[cur];
        short8 av[4], bv[2];
#pragma unroll
        for (int i = 0; i < 4; i++) av[i] = *(const short8*)&as[aoff0 + i * 16 * 64];
#pragma unroll
        for (int i = 0; i < 2; i++) bv[i] = *(const short8*)&bs[boff0 + i * 16 * 64];
        __builtin_amdgcn_s_setprio(1);
#pragma unroll
        for (int mi = 0; mi < 4; mi++)
#pragma unroll
            for (int ni = 0; ni < 2; ni++)
                acc[mi][ni] = __builtin_amdgcn_mfma_f32_16x16x32_bf16(av[mi], bv[ni], acc[mi][ni], 0, 0, 0);
        __builtin_amdgcn_s_setprio(0);
#pragma unroll
        for (int i = 0; i < 4; i++) av[i] = *(const short8*)&as[aoff1 + i * 16 * 64];
#pragma unroll
        for (int i = 0; i < 2; i++) bv[i] = *(const short8*)&bs[boff1 + i * 16 * 64];
        __builtin_amdgcn_s_setprio(1);
#pragma unroll
        for (int mi = 0; mi < 4; mi++)
#pragma unroll
            for (int ni = 0; ni < 2; ni++)
                acc[mi][ni] = __builtin_amdgcn_mfma_f32_16x16x32_bf16(av[mi], bv[ni], acc[mi][ni], 0, 0, 0);
        __builtin_amdgcn_s_setprio(0);
        __builtin_amdgcn_sched_barrier(0);
        __builtin_amdgcn_s_barrier();
    }

    int rl = (lane >> 4) * 4, col = lane & 15;

    if (EPI == 6) {
        float s_[4][4];
#pragma unroll
        for (int mi = 0; mi < 4; mi++)
#pragma unroll
            for (int j = 0; j < 4; j++) s_[mi][j] = 0.f;
#pragma unroll
        for (int mi = 0; mi < 4; mi++)
#pragma unroll
            for (int ni = 0; ni < 2; ni++) {
                int n = n0 + wn + ni * 16 + col;
                int r = wm + mi * 16 + rl;
#pragma unroll
                for (int j = 0; j < 4; j++) {
                    float e = __expf(acc[mi][ni][j]);
                    Cb[coff + (long)(m0 + r + j) * ldc + n] = f2bf(e);
                    s_[mi][j] += e;
                }
            }
#pragma unroll
        for (int off = 1; off < 16; off <<= 1)
#pragma unroll
            for (int mi = 0; mi < 4; mi++)
#pragma unroll
                for (int j = 0; j < 4; j++) s_[mi][j] += __shfl_xor(s_[mi][j], off);
        int li = lane & 15;
        int smi = li >> 2, sj = li & 3;
        int row = wm + smi * 16 + (lane >> 4) * 4 + sj;
        Lp[((long)(bz * 16 + blockIdx.x) * 4 + (w & 3)) * WS + m0 + row] = s_[smi][sj];
        return;
    }

#pragma unroll
    for (int mi = 0; mi < 4; mi++) {
#pragma unroll
        for (int ni = 0; ni < 2; ni++) {
            int n = n0 + wn + ni * 16 + col;
            float bvv = (EPI == 0 || EPI == 1 || EPI == 5) ? bias[n] : 0.f;
            if (EPI == 1) {
                int m = m0 + wm + mi * 16 + rl;
                short4v o;
#pragma unroll
                for (int j = 0; j < 4; j++) o[j] = f2bf(acc[mi][ni][j] + bvv);
                *(short4v*)&Cb[((long)(m >> 11) * WD + n) * WS + (m & (WS - 1))] = o;
            } else {
#pragma unroll
                for (int j = 0; j < 4; j++) {
                    int r = wm + mi * 16 + rl + j;
                    if (EPI == 7) {
                        float v = acc[mi][ni][j] * lds_l[r];
                        Cb[coff + (long)(m0 + r) * ldc + n] = f2bf(v);
                    } else {
                        float v = (acc[mi][ni][j] + bvv) * scale;
                        if (EPI == 5) Cf[coff + (long)(m0 + r) * ldc + n] = v;
                        else Cb[coff + (long)(m0 + r) * ldc + n] = f2bf(v);
                    }
                }
            }
        }
    }
}

// ---------------- old 64x64 GEMM, kept for FFN1 (N=64) ----------------
template<int EPI, bool BT>
__global__ __launch_bounds__(256) void gemm_k(
    const short* __restrict__ A, const short* __restrict__ Bm,
    const float* __restrict__ bias, float* __restrict__ Cf, short* __restrict__ Cb,
    int M, int N, int K, int lda, int ldb, int ldc,
    long sA, long sB, long sC, float scale, int b0)
{
    __shared__ short As[64][40];
    __shared__ short Bs[64][40];
    int tid = threadIdx.x;
    int bz = b0 + blockIdx.z;
    const short* Ab = A + (long)bz * sA;
    const short* Bb = Bm + (long)bz * sB;
    long coff = (long)bz * sC;
    int m0 = blockIdx.y * 64, n0 = blockIdx.x * 64;

    floatx4 acc[4];
#pragma unroll
    for (int c = 0; c < 4; c++) acc[c] = (floatx4){0.f, 0.f, 0.f, 0.f};

    int lane = tid & 63, w = tid >> 6;
    int arow = w * 16 + (lane & 15);
    int koff = (lane >> 4) * 8;

    for (int kt = 0; kt < K; kt += 32) {
        {
            int r = tid >> 2, kc = (tid & 3) * 8;
            short8 av = *(const short8*)(Ab + (long)(m0 + r) * lda + kt + kc);
            *(short8*)&As[r][kc] = av;
        }
        if (BT) {
            int kk = tid >> 3, nn = (tid & 7) * 8;
            short8 bv = *(const short8*)(Bb + (long)(kt + kk) * ldb + n0 + nn);
#pragma unroll
            for (int e = 0; e < 8; e++) Bs[nn + e][kk] = bv[e];
        } else {
            int r = tid >> 2, kc = (tid & 3) * 8;
            short8 bv = *(const short8*)(Bb + (long)(n0 + r) * ldb + kt + kc);
            *(short8*)&Bs[r][kc] = bv;
        }
        __syncthreads();
        short8 a = *(const short8*)&As[arow][koff];
#pragma unroll
        for (int c = 0; c < 4; c++) {
            short8 b = *(const short8*)&Bs[c * 16 + (lane & 15)][koff];
            acc[c] = __builtin_amdgcn_mfma_f32_16x16x32_bf16(a, b, acc[c], 0, 0, 0);
        }
        __syncthreads();
    }

    int rl = (lane >> 4) * 4, col = lane & 15;
    int mb = m0 + w * 16 + rl;
#pragma unroll
    for (int c = 0; c < 4; c++) {
        int n = n0 + c * 16 + col;
        float bvv = (EPI == 0 || EPI == 4 || EPI == 5) ? bias[n] : 0.f;
#pragma unroll
        for (int j = 0; j < 4; j++) {
            int m = mb + j;
            float v = acc[c][j] + bvv;
            if (EPI == 4) v = fmaxf(v, 0.f);
            v *= scale;
            if (EPI == 2 || EPI == 5) {
                Cf[coff + (long)m * ldc + n] = v;
            } else {
                Cb[coff + (long)m * ldc + n] = f2bf(v);
            }
        }
    }
}

__global__ __launch_bounds__(256) void ln_k(float* __restrict__ h,
                                            const float* __restrict__ ff,
                                            const float* __restrict__ g1, const float* __restrict__ bb1,
                                            const float* __restrict__ g2, const float* __restrict__ bb2,
                                            short* __restrict__ hbf,
                                            float* __restrict__ outp)
{
    long r = blockIdx.x;
    int i = threadIdx.x;
    float2 hv = *(const float2*)&h[r * WD + i * 2];
    float2 fv = *(const float2*)&ff[r * WD + i * 2];
    float a = hv.x + fv.x, b = hv.y + fv.y;
    float mu = block_reduce(a + b, false) * (1.f / WD);
    float da = a - mu, db = b - mu;
    float var = block_reduce(da * da + db * db, false) * (1.f / WD);
    float rs = rsqrtf(var + 1e-5f);
    float y0 = da * rs * g1[2 * i] + bb1[2 * i];
    float y1 = db * rs * g1[2 * i + 1] + bb1[2 * i + 1];
    float mu2 = block_reduce(y0 + y1, false) * (1.f / WD);
    float d0 = y0 - mu2, d1 = y1 - mu2;
    float var2 = block_reduce(d0 * d0 + d1 * d1, false) * (1.f / WD);
    float rs2 = rsqrtf(var2 + 1e-5f);
    float z0 = d0 * rs2 * g2[2 * i] + bb2[2 * i];
    float z1 = d1 * rs2 * g2[2 * i + 1] + bb2[2 * i + 1];
    *(float2*)&h[r * WD + i * 2] = make_float2(z0, z1);
    hbf[r * WD + i * 2] = f2bf(z0);
    hbf[r * WD + i * 2 + 1] = f2bf(z1);
    if (outp) *(float2*)&outp[r * WD + i * 2] = make_float2(z0, z1);
}

__global__ void conv_x_k(const float* __restrict__ x, float* __restrict__ h,
                         short* __restrict__ hbf, int n4)
{
    int i = blockIdx.x * blockDim.x + threadIdx.x;
    for (; i < n4; i += gridDim.x * blockDim.x) {
        float4 v = ((const float4*)x)[i];
        ((float4*)h)[i] = v;
        short4v o;
        o[0] = f2bf(v.x); o[1] = f2bf(v.y); o[2] = f2bf(v.z); o[3] = f2bf(v.w);
        *(short4v*)&hbf[i * 4] = o;
    }
}

__global__ void conv_w_k(const float* __restrict__ x, short* __restrict__ w, int n4)
{
    int i = blockIdx.x * blockDim.x + threadIdx.x;
    for (; i < n4; i += gridDim.x * blockDim.x) {
        float4 v = ((const float4*)x)[i];
        short4v o;
        o[0] = f2bf(v.x); o[1] = f2bf(v.y); o[2] = f2bf(v.z); o[3] = f2bf(v.w);
        *(short4v*)&w[i * 4] = o;
    }
}

// W [R][C] f32 -> Wt [C][R] bf16
__global__ __launch_bounds__(256) void transpose_w_k(const float* __restrict__ W,
                                                     short* __restrict__ Wt, int R, int C)
{
    __shared__ short t[32][33];
    int c0 = blockIdx.x * 32, r0 = blockIdx.y * 32;
    int tx = threadIdx.x & 31, ty = threadIdx.x >> 5; // 32x8
#pragma unroll
    for (int i = 0; i < 32; i += 8)
        t[ty + i][tx] = f2bf(W[(long)(r0 + ty + i) * C + c0 + tx]);
    __syncthreads();
#pragma unroll
    for (int i = 0; i < 32; i += 8)
        Wt[(long)(c0 + ty + i) * R + r0 + tx] = t[tx][ty + i];
}

extern "C" void kernel_launch(void* const* d_in, const int* in_sizes, int n_in,
                              void* d_out, int out_size, void* d_ws, size_t ws_size,
                              hipStream_t stream)
{
    const float* x   = (const float*)d_in[0];
    const float* Wq  = (const float*)d_in[1];
    const float* bq  = (const float*)d_in[2];
    const float* Wk  = (const float*)d_in[3];
    const float* bk  = (const float*)d_in[4];
    const float* Wv  = (const float*)d_in[5];
    const float* bv  = (const float*)d_in[6];
    const float* W1  = (const float*)d_in[7];
    const float* b1  = (const float*)d_in[8];
    const float* W2  = (const float*)d_in[9];
    const float* b2  = (const float*)d_in[10];
    const float* g1  = (const float*)d_in[11];
    const float* lb1 = (const float*)d_in[12];
    const float* g2  = (const float*)d_in[13];
    const float* lb2 = (const float*)d_in[14];
    float* out = (float*)d_out;

    char* p = (char*)d_ws;
    auto carve = [&](size_t bytes) -> char* {
        char* r = p;
        p += (bytes + 255) & ~(size_t)255;
        return r;
    };
    float* h    = (float*)carve((size_t)WB * WS * WD * 4);
    short* hbf  = (short*)carve((size_t)WB * WS * WD * 2);
    short* kbf  = (short*)carve((size_t)WB * WS * WD * 2);
    short* vt   = (short*)carve((size_t)WB * WS * WD * 2);
    short* qbf  = (short*)carve((size_t)WB * WS * WD * 2);
    short* abf  = (short*)carve((size_t)WB * WS * WD * 2);
    short* fhbf = (short*)carve((size_t)WB * WS * WHID * 2);
    short* wqt  = (short*)carve((size_t)WD * WD * 2);
    short* wkt  = (short*)carve((size_t)WD * WD * 2);
    short* wvt  = (short*)carve((size_t)WD * WD * 2);
    short* w1b  = (short*)carve((size_t)WD * WHID * 2);
    short* w2t  = (short*)carve((size_t)WHID * WD * 2);
    float* Lp   = (float*)carve((size_t)WB * 64 * WS * 4);
    size_t used_base = (size_t)(p - (char*)d_ws);
    size_t full_extra = (size_t)WB * WS * WS * 2 + 1024;
    bool full = ws_size >= used_base + full_extra;
    short* pbf;
    if (full) {
        pbf = (short*)carve((size_t)WB * WS * WS * 2);
    } else {
        pbf = (short*)carve((size_t)WS * WS * 2);
    }

    const int M = WB * WS;
    const float sc_attn = 0.125f;           // 1/sqrt(HID=64), folded into Q proj (exact pow2)
    const float sc_out  = 0.04419417382f;   // 1/sqrt(D=512)

    conv_x_k<<<2048, 256, 0, stream>>>(x, h, hbf, WB * WS * WD / 4);
    transpose_w_k<<<dim3(WD / 32, WD / 32), 256, 0, stream>>>(Wq, wqt, WD, WD);
    transpose_w_k<<<dim3(WD / 32, WD / 32), 256, 0, stream>>>(Wk, wkt, WD, WD);
    transpose_w_k<<<dim3(WD / 32, WD / 32), 256, 0, stream>>>(Wv, wvt, WD, WD);
    transpose_w_k<<<dim3(WD / 32, WHID / 32), 256, 0, stream>>>(W2, w2t, WHID, WD);
    conv_w_k<<<64, 256, 0, stream>>>(W1, w1b, WD * WHID / 4);

    // k = x @ Wk + bk  (bf16, row-major [B*S][D])
    gemm8_k<0><<<dim3(WD / 128, M / 128, 1), 512, 0, stream>>>(
        hbf, wkt, bk, nullptr, kbf, WD, WD, WD, WD, 0, 0, 0, 1.0f, 0, nullptr);
    // v = x @ Wv + bv  (bf16, transposed per batch: [B][D][S])
    gemm8_k<1><<<dim3(WD / 128, M / 128, 1), 512, 0, stream>>>(
        hbf, wvt, bv, nullptr, vt, WD, WD, WD, WD, 0, 0, 0, 1.0f, 0, nullptr);

    for (int l = 0; l < NLAYER; l++) {
        // q = (h @ Wq + bq) * sc_attn
        gemm8_k<0><<<dim3(WD / 128, M / 128, 1), 512, 0, stream>>>(
            hbf, wqt, bq, nullptr, qbf, WD, WD, WD, WD, 0, 0, 0, sc_attn, 0, nullptr);

        if (full) {
            // P = exp(q @ k^T), row-sum partials -> Lp
            gemm8_k<6><<<dim3(WS / 128, WS / 128, WB), 512, 0, stream>>>(
                qbf, kbf, nullptr, nullptr, pbf, WD, WD, WD, WS,
                (long)WS * WD, (long)WS * WD, (long)WS * WS, 1.0f, 0, Lp);
            // attn = (P @ V) * sc_out / l
            gemm8_k<7><<<dim3(WD / 128, WS / 128, WB), 512, 0, stream>>>(
                pbf, vt, nullptr, nullptr, abf, WS, WS, WS, WD,
                (long)WS * WS, (long)WD * WS, (long)WS * WD, sc_out, 0, Lp);
        } else {
            for (int b = 0; b < WB; b++) {
                gemm8_k<6><<<dim3(WS / 128, WS / 128, 1), 512, 0, stream>>>(
                    qbf, kbf, nullptr, nullptr, pbf, WD, WD, WD, WS,
                    (long)WS * WD, (long)WS * WD, 0, 1.0f, b, Lp);
                gemm8_k<7><<<dim3(WD / 128, WS / 128, 1), 512, 0, stream>>>(
                    pbf, vt, nullptr, nullptr, abf, WS, WS, WS, WD,
                    0, (long)WD * WS, (long)WS * WD, sc_out, b, Lp);
            }
        }

        // ffh = relu(attn @ W1 + b1)   (N=64 -> old 64x64 kernel)
        gemm_k<4, true><<<dim3(WHID / 64, M / 64, 1), 256, 0, stream>>>(
            abf, w1b, b1, nullptr, fhbf, M, WHID, WD, WD, WHID, WHID, 0, 0, 0, 1.0f, 0);
        // ff = ffh @ W2 + b2  (fp32, into d_out as scratch)
        gemm8_k<5><<<dim3(WD / 128, M / 128, 1), 512, 0, stream>>>(
            fhbf, w2t, b2, out, nullptr, WHID, WHID, WHID, WD, 0, 0, 0, 1.0f, 0, nullptr);
        // h = LN2(LN1(h + ff)); last layer also writes d_out
        ln_k<<<M, 256, 0, stream>>>(h, out, g1, lb1, g2, lb2, hbf,
                                    (l == NLAYER - 1) ? out : nullptr);
    }
}

// Round 6
// 756.182 us; speedup vs baseline: 1.1939x; 1.1939x over previous
//
#include <hip/hip_runtime.h>
#include <hip/hip_bf16.h>
#include <math.h>

#define WB 4
#define WS 2048
#define WD 512
#define WHID 64
#define NLAYER 6

typedef __attribute__((ext_vector_type(8))) short short8;
typedef __attribute__((ext_vector_type(4))) short short4v;
typedef __attribute__((ext_vector_type(4))) float floatx4;

__device__ __forceinline__ short f2bf(float f) {
    union { float f; unsigned u; } x; x.f = f;
    unsigned r = (x.u + 0x7fffu + ((x.u >> 16) & 1u)) >> 16;
    return (short)r;
}

__device__ __forceinline__ void gl_lds16(const short* g, short* l) {
    __builtin_amdgcn_global_load_lds(
        (const __attribute__((address_space(1))) unsigned*)g,
        (__attribute__((address_space(3))) unsigned*)l, 16, 0, 0);
}

__device__ __forceinline__ float block_reduce(float v, bool is_max) {
    __shared__ float tmp[4];
    int lane = threadIdx.x & 63, w = threadIdx.x >> 6;
#pragma unroll
    for (int off = 32; off; off >>= 1) {
        float o = __shfl_xor(v, off);
        v = is_max ? fmaxf(v, o) : v + o;
    }
    __syncthreads();
    if (lane == 0) tmp[w] = v;
    __syncthreads();
    int nw = blockDim.x >> 6;
    float r = tmp[0];
    for (int i = 1; i < nw; i++) r = is_max ? fmaxf(r, tmp[i]) : r + tmp[i];
    return r;
}

// ---------- 128x128 NT GEMM, 8 waves, BK=64, 2-buffer counted-vmcnt pipeline ----------
// A: [M][K] bf16 row-major, B: [N][K] bf16 row-major. K % 64 == 0.
// LDS: row r, 16B-block b holds global block (b ^ (r&7)); linear dest for
// global_load_lds, swizzle realized via inverse-permuted per-lane GLOBAL source.
// Pipeline: iter t issues stage(t+1) into buf^1, waits vmcnt(4) (tile t landed,
// tile t+1 stays in flight across compute), barrier, compute, plain barrier.
// EPI: 0 = bf16 ((acc+bias)*scale); 1 = bf16 transposed into vt[B][D][S] (+bias);
//      5 = f32 (+bias); 6 = QK: bf16 exp(acc) + row-sum partials into Lp;
//      7 = PV: bf16 acc * (scale / l[row]) with l reduced from Lp.
template<int EPI>
__global__ __launch_bounds__(512) void gemm8_k(
    const short* __restrict__ A, const short* __restrict__ Bm,
    const float* __restrict__ bias, float* __restrict__ Cf, short* __restrict__ Cb,
    int K, int lda, int ldb, int ldc,
    long sA, long sB, long sC, float scale, int b0, float* __restrict__ Lp)
{
    __shared__ __align__(16) short As[2][128 * 64];
    __shared__ __align__(16) short Bs[2][128 * 64];
    __shared__ float lds_l[128];
    int tid = threadIdx.x;
    int bz = b0 + blockIdx.z;
    int m0 = blockIdx.y * 128, n0 = blockIdx.x * 128;
    const short* Ab = A + (long)bz * sA + (long)m0 * lda;
    const short* Bb = Bm + (long)bz * sB + (long)n0 * ldb;
    long coff = (long)bz * sC;

    if (EPI == 7 && tid < 128) {
        float s = 0.f;
        const float* lp = Lp + (long)bz * 64 * WS + m0 + tid;
#pragma unroll 8
        for (int p2 = 0; p2 < 64; p2++) s += lp[(long)p2 * WS];
        lds_l[tid] = scale / s;
    }

    int lane = tid & 63, w = tid >> 6;
    int wm = (w >> 2) * 64, wn = (w & 3) * 32;

    floatx4 acc[4][2];
#pragma unroll
    for (int mi = 0; mi < 4; mi++)
#pragma unroll
        for (int ni = 0; ni < 2; ni++) acc[mi][ni] = (floatx4){0.f, 0.f, 0.f, 0.f};

    // staging: thread covers chunks tid and tid+512 (rows r0 and r0+64, same block)
    int r0 = tid >> 3;
    int sblk = (tid & 7) ^ (r0 & 7);
    const short* ga0 = Ab + (long)r0 * lda + sblk * 8;
    const short* gb0 = Bb + (long)r0 * ldb + sblk * 8;
    long lda64 = (long)64 * lda, ldb64 = (long)64 * ldb;

    // fragment read offsets (swizzled)
    int arow = wm + (lane & 15);
    int brow = wn + (lane & 15);
    int a7 = arow & 7, b7 = brow & 7;
    int kb = lane >> 4;  // 0..3
    int aoff0 = arow * 64 + ((kb ^ a7) * 8);
    int aoff1 = arow * 64 + (((kb + 4) ^ a7) * 8);
    int boff0 = brow * 64 + ((kb ^ b7) * 8);
    int boff1 = brow * 64 + (((kb + 4) ^ b7) * 8);

    int nt = K >> 6;

    auto stage = [&](int t, int b) {
        const short* ga = ga0 + t * 64;
        const short* gb = gb0 + t * 64;
        gl_lds16(ga, &As[b][tid * 8]);
        gl_lds16(ga + lda64, &As[b][(tid + 512) * 8]);
        gl_lds16(gb, &Bs[b][tid * 8]);
        gl_lds16(gb + ldb64, &Bs[b][(tid + 512) * 8]);
    };

    stage(0, 0);

    for (int t = 0; t < nt; t++) {
        int cur = t & 1;
        if (t + 1 < nt) {
            stage(t + 1, cur ^ 1);
            asm volatile("s_waitcnt vmcnt(4)" ::: "memory");
        } else {
            asm volatile("s_waitcnt vmcnt(0)" ::: "memory");
        }
        __builtin_amdgcn_s_barrier();
        __builtin_amdgcn_sched_barrier(0);
        const short* as = As[cur];
        const short* bs = Bs[cur];
        short8 av[4], bv[2];
#pragma unroll
        for (int i = 0; i < 4; i++) av[i] = *(const short8*)&as[aoff0 + i * 16 * 64];
#pragma unroll
        for (int i = 0; i < 2; i++) bv[i] = *(const short8*)&bs[boff0 + i * 16 * 64];
#pragma unroll
        for (int mi = 0; mi < 4; mi++)
#pragma unroll
            for (int ni = 0; ni < 2; ni++)
                acc[mi][ni] = __builtin_amdgcn_mfma_f32_16x16x32_bf16(av[mi], bv[ni], acc[mi][ni], 0, 0, 0);
#pragma unroll
        for (int i = 0; i < 4; i++) av[i] = *(const short8*)&as[aoff1 + i * 16 * 64];
#pragma unroll
        for (int i = 0; i < 2; i++) bv[i] = *(const short8*)&bs[boff1 + i * 16 * 64];
#pragma unroll
        for (int mi = 0; mi < 4; mi++)
#pragma unroll
            for (int ni = 0; ni < 2; ni++)
                acc[mi][ni] = __builtin_amdgcn_mfma_f32_16x16x32_bf16(av[mi], bv[ni], acc[mi][ni], 0, 0, 0);
        __builtin_amdgcn_sched_barrier(0);
        __builtin_amdgcn_s_barrier();
    }

    int rl = (lane >> 4) * 4, col = lane & 15;

    if (EPI == 6) {
        float s_[4][4];
#pragma unroll
        for (int mi = 0; mi < 4; mi++)
#pragma unroll
            for (int j = 0; j < 4; j++) s_[mi][j] = 0.f;
#pragma unroll
        for (int mi = 0; mi < 4; mi++)
#pragma unroll
            for (int ni = 0; ni < 2; ni++) {
                int n = n0 + wn + ni * 16 + col;
                int r = wm + mi * 16 + rl;
#pragma unroll
                for (int j = 0; j < 4; j++) {
                    float e = __expf(acc[mi][ni][j]);
                    Cb[coff + (long)(m0 + r + j) * ldc + n] = f2bf(e);
                    s_[mi][j] += e;
                }
            }
#pragma unroll
        for (int off = 1; off < 16; off <<= 1)
#pragma unroll
            for (int mi = 0; mi < 4; mi++)
#pragma unroll
                for (int j = 0; j < 4; j++) s_[mi][j] += __shfl_xor(s_[mi][j], off);
        int li = lane & 15;
        int smi = li >> 2, sj = li & 3;
        int row = wm + smi * 16 + (lane >> 4) * 4 + sj;
        Lp[((long)(bz * 16 + blockIdx.x) * 4 + (w & 3)) * WS + m0 + row] = s_[smi][sj];
        return;
    }

#pragma unroll
    for (int mi = 0; mi < 4; mi++) {
#pragma unroll
        for (int ni = 0; ni < 2; ni++) {
            int n = n0 + wn + ni * 16 + col;
            float bvv = (EPI == 0 || EPI == 1 || EPI == 5) ? bias[n] : 0.f;
            if (EPI == 1) {
                int m = m0 + wm + mi * 16 + rl;
                short4v o;
#pragma unroll
                for (int j = 0; j < 4; j++) o[j] = f2bf(acc[mi][ni][j] + bvv);
                *(short4v*)&Cb[((long)(m >> 11) * WD + n) * WS + (m & (WS - 1))] = o;
            } else {
#pragma unroll
                for (int j = 0; j < 4; j++) {
                    int r = wm + mi * 16 + rl + j;
                    if (EPI == 7) {
                        float v = acc[mi][ni][j] * lds_l[r];
                        Cb[coff + (long)(m0 + r) * ldc + n] = f2bf(v);
                    } else {
                        float v = (acc[mi][ni][j] + bvv) * scale;
                        if (EPI == 5) Cf[coff + (long)(m0 + r) * ldc + n] = v;
                        else Cb[coff + (long)(m0 + r) * ldc + n] = f2bf(v);
                    }
                }
            }
        }
    }
}

// ---------------- old 64x64 GEMM, kept for FFN1 (N=64) ----------------
template<int EPI, bool BT>
__global__ __launch_bounds__(256) void gemm_k(
    const short* __restrict__ A, const short* __restrict__ Bm,
    const float* __restrict__ bias, float* __restrict__ Cf, short* __restrict__ Cb,
    int M, int N, int K, int lda, int ldb, int ldc,
    long sA, long sB, long sC, float scale, int b0)
{
    __shared__ short As[64][40];
    __shared__ short Bs[64][40];
    int tid = threadIdx.x;
    int bz = b0 + blockIdx.z;
    const short* Ab = A + (long)bz * sA;
    const short* Bb = Bm + (long)bz * sB;
    long coff = (long)bz * sC;
    int m0 = blockIdx.y * 64, n0 = blockIdx.x * 64;

    floatx4 acc[4];
#pragma unroll
    for (int c = 0; c < 4; c++) acc[c] = (floatx4){0.f, 0.f, 0.f, 0.f};

    int lane = tid & 63, w = tid >> 6;
    int arow = w * 16 + (lane & 15);
    int koff = (lane >> 4) * 8;

    for (int kt = 0; kt < K; kt += 32) {
        {
            int r = tid >> 2, kc = (tid & 3) * 8;
            short8 av = *(const short8*)(Ab + (long)(m0 + r) * lda + kt + kc);
            *(short8*)&As[r][kc] = av;
        }
        if (BT) {
            int kk = tid >> 3, nn = (tid & 7) * 8;
            short8 bv = *(const short8*)(Bb + (long)(kt + kk) * ldb + n0 + nn);
#pragma unroll
            for (int e = 0; e < 8; e++) Bs[nn + e][kk] = bv[e];
        } else {
            int r = tid >> 2, kc = (tid & 3) * 8;
            short8 bv = *(const short8*)(Bb + (long)(n0 + r) * ldb + kt + kc);
            *(short8*)&Bs[r][kc] = bv;
        }
        __syncthreads();
        short8 a = *(const short8*)&As[arow][koff];
#pragma unroll
        for (int c = 0; c < 4; c++) {
            short8 b = *(const short8*)&Bs[c * 16 + (lane & 15)][koff];
            acc[c] = __builtin_amdgcn_mfma_f32_16x16x32_bf16(a, b, acc[c], 0, 0, 0);
        }
        __syncthreads();
    }

    int rl = (lane >> 4) * 4, col = lane & 15;
    int mb = m0 + w * 16 + rl;
#pragma unroll
    for (int c = 0; c < 4; c++) {
        int n = n0 + c * 16 + col;
        float bvv = (EPI == 0 || EPI == 4 || EPI == 5) ? bias[n] : 0.f;
#pragma unroll
        for (int j = 0; j < 4; j++) {
            int m = mb + j;
            float v = acc[c][j] + bvv;
            if (EPI == 4) v = fmaxf(v, 0.f);
            v *= scale;
            if (EPI == 2 || EPI == 5) {
                Cf[coff + (long)m * ldc + n] = v;
            } else {
                Cb[coff + (long)m * ldc + n] = f2bf(v);
            }
        }
    }
}

__global__ __launch_bounds__(256) void ln_k(float* __restrict__ h,
                                            const float* __restrict__ ff,
                                            const float* __restrict__ g1, const float* __restrict__ bb1,
                                            const float* __restrict__ g2, const float* __restrict__ bb2,
                                            short* __restrict__ hbf,
                                            float* __restrict__ outp)
{
    long r = blockIdx.x;
    int i = threadIdx.x;
    float2 hv = *(const float2*)&h[r * WD + i * 2];
    float2 fv = *(const float2*)&ff[r * WD + i * 2];
    float a = hv.x + fv.x, b = hv.y + fv.y;
    float mu = block_reduce(a + b, false) * (1.f / WD);
    float da = a - mu, db = b - mu;
    float var = block_reduce(da * da + db * db, false) * (1.f / WD);
    float rs = rsqrtf(var + 1e-5f);
    float y0 = da * rs * g1[2 * i] + bb1[2 * i];
    float y1 = db * rs * g1[2 * i + 1] + bb1[2 * i + 1];
    float mu2 = block_reduce(y0 + y1, false) * (1.f / WD);
    float d0 = y0 - mu2, d1 = y1 - mu2;
    float var2 = block_reduce(d0 * d0 + d1 * d1, false) * (1.f / WD);
    float rs2 = rsqrtf(var2 + 1e-5f);
    float z0 = d0 * rs2 * g2[2 * i] + bb2[2 * i];
    float z1 = d1 * rs2 * g2[2 * i + 1] + bb2[2 * i + 1];
    *(float2*)&h[r * WD + i * 2] = make_float2(z0, z1);
    hbf[r * WD + i * 2] = f2bf(z0);
    hbf[r * WD + i * 2 + 1] = f2bf(z1);
    if (outp) *(float2*)&outp[r * WD + i * 2] = make_float2(z0, z1);
}

__global__ void conv_x_k(const float* __restrict__ x, float* __restrict__ h,
                         short* __restrict__ hbf, int n4)
{
    int i = blockIdx.x * blockDim.x + threadIdx.x;
    for (; i < n4; i += gridDim.x * blockDim.x) {
        float4 v = ((const float4*)x)[i];
        ((float4*)h)[i] = v;
        short4v o;
        o[0] = f2bf(v.x); o[1] = f2bf(v.y); o[2] = f2bf(v.z); o[3] = f2bf(v.w);
        *(short4v*)&hbf[i * 4] = o;
    }
}

__global__ void conv_w_k(const float* __restrict__ x, short* __restrict__ w, int n4)
{
    int i = blockIdx.x * blockDim.x + threadIdx.x;
    for (; i < n4; i += gridDim.x * blockDim.x) {
        float4 v = ((const float4*)x)[i];
        short4v o;
        o[0] = f2bf(v.x); o[1] = f2bf(v.y); o[2] = f2bf(v.z); o[3] = f2bf(v.w);
        *(short4v*)&w[i * 4] = o;
    }
}

// W [R][C] f32 -> Wt [C][R] bf16
__global__ __launch_bounds__(256) void transpose_w_k(const float* __restrict__ W,
                                                     short* __restrict__ Wt, int R, int C)
{
    __shared__ short t[32][33];
    int c0 = blockIdx.x * 32, r0 = blockIdx.y * 32;
    int tx = threadIdx.x & 31, ty = threadIdx.x >> 5; // 32x8
#pragma unroll
    for (int i = 0; i < 32; i += 8)
        t[ty + i][tx] = f2bf(W[(long)(r0 + ty + i) * C + c0 + tx]);
    __syncthreads();
#pragma unroll
    for (int i = 0; i < 32; i += 8)
        Wt[(long)(c0 + ty + i) * R + r0 + tx] = t[tx][ty + i];
}

extern "C" void kernel_launch(void* const* d_in, const int* in_sizes, int n_in,
                              void* d_out, int out_size, void* d_ws, size_t ws_size,
                              hipStream_t stream)
{
    const float* x   = (const float*)d_in[0];
    const float* Wq  = (const float*)d_in[1];
    const float* bq  = (const float*)d_in[2];
    const float* Wk  = (const float*)d_in[3];
    const float* bk  = (const float*)d_in[4];
    const float* Wv  = (const float*)d_in[5];
    const float* bv  = (const float*)d_in[6];
    const float* W1  = (const float*)d_in[7];
    const float* b1  = (const float*)d_in[8];
    const float* W2  = (const float*)d_in[9];
    const float* b2  = (const float*)d_in[10];
    const float* g1  = (const float*)d_in[11];
    const float* lb1 = (const float*)d_in[12];
    const float* g2  = (const float*)d_in[13];
    const float* lb2 = (const float*)d_in[14];
    float* out = (float*)d_out;

    char* p = (char*)d_ws;
    auto carve = [&](size_t bytes) -> char* {
        char* r = p;
        p += (bytes + 255) & ~(size_t)255;
        return r;
    };
    float* h    = (float*)carve((size_t)WB * WS * WD * 4);
    short* hbf  = (short*)carve((size_t)WB * WS * WD * 2);
    short* kbf  = (short*)carve((size_t)WB * WS * WD * 2);
    short* vt   = (short*)carve((size_t)WB * WS * WD * 2);
    short* qbf  = (short*)carve((size_t)WB * WS * WD * 2);
    short* abf  = (short*)carve((size_t)WB * WS * WD * 2);
    short* fhbf = (short*)carve((size_t)WB * WS * WHID * 2);
    short* wqt  = (short*)carve((size_t)WD * WD * 2);
    short* wkt  = (short*)carve((size_t)WD * WD * 2);
    short* wvt  = (short*)carve((size_t)WD * WD * 2);
    short* w1b  = (short*)carve((size_t)WD * WHID * 2);
    short* w2t  = (short*)carve((size_t)WHID * WD * 2);
    float* Lp   = (float*)carve((size_t)WB * 64 * WS * 4);
    size_t used_base = (size_t)(p - (char*)d_ws);
    size_t full_extra = (size_t)WB * WS * WS * 2 + 1024;
    bool full = ws_size >= used_base + full_extra;
    short* pbf;
    if (full) {
        pbf = (short*)carve((size_t)WB * WS * WS * 2);
    } else {
        pbf = (short*)carve((size_t)WS * WS * 2);
    }

    const int M = WB * WS;
    const float sc_attn = 0.125f;           // 1/sqrt(HID=64), folded into Q proj (exact pow2)
    const float sc_out  = 0.04419417382f;   // 1/sqrt(D=512)

    conv_x_k<<<2048, 256, 0, stream>>>(x, h, hbf, WB * WS * WD / 4);
    transpose_w_k<<<dim3(WD / 32, WD / 32), 256, 0, stream>>>(Wq, wqt, WD, WD);
    transpose_w_k<<<dim3(WD / 32, WD / 32), 256, 0, stream>>>(Wk, wkt, WD, WD);
    transpose_w_k<<<dim3(WD / 32, WD / 32), 256, 0, stream>>>(Wv, wvt, WD, WD);
    transpose_w_k<<<dim3(WD / 32, WHID / 32), 256, 0, stream>>>(W2, w2t, WHID, WD);
    conv_w_k<<<64, 256, 0, stream>>>(W1, w1b, WD * WHID / 4);

    // k = x @ Wk + bk  (bf16, row-major [B*S][D])
    gemm8_k<0><<<dim3(WD / 128, M / 128, 1), 512, 0, stream>>>(
        hbf, wkt, bk, nullptr, kbf, WD, WD, WD, WD, 0, 0, 0, 1.0f, 0, nullptr);
    // v = x @ Wv + bv  (bf16, transposed per batch: [B][D][S])
    gemm8_k<1><<<dim3(WD / 128, M / 128, 1), 512, 0, stream>>>(
        hbf, wvt, bv, nullptr, vt, WD, WD, WD, WD, 0, 0, 0, 1.0f, 0, nullptr);

    for (int l = 0; l < NLAYER; l++) {
        // q = (h @ Wq + bq) * sc_attn
        gemm8_k<0><<<dim3(WD / 128, M / 128, 1), 512, 0, stream>>>(
            hbf, wqt, bq, nullptr, qbf, WD, WD, WD, WD, 0, 0, 0, sc_attn, 0, nullptr);

        if (full) {
            // P = exp(q @ k^T), row-sum partials -> Lp
            gemm8_k<6><<<dim3(WS / 128, WS / 128, WB), 512, 0, stream>>>(
                qbf, kbf, nullptr, nullptr, pbf, WD, WD, WD, WS,
                (long)WS * WD, (long)WS * WD, (long)WS * WS, 1.0f, 0, Lp);
            // attn = (P @ V) * sc_out / l
            gemm8_k<7><<<dim3(WD / 128, WS / 128, WB), 512, 0, stream>>>(
                pbf, vt, nullptr, nullptr, abf, WS, WS, WS, WD,
                (long)WS * WS, (long)WD * WS, (long)WS * WD, sc_out, 0, Lp);
        } else {
            for (int b = 0; b < WB; b++) {
                gemm8_k<6><<<dim3(WS / 128, WS / 128, 1), 512, 0, stream>>>(
                    qbf, kbf, nullptr, nullptr, pbf, WD, WD, WD, WS,
                    (long)WS * WD, (long)WS * WD, 0, 1.0f, b, Lp);
                gemm8_k<7><<<dim3(WD / 128, WS / 128, 1), 512, 0, stream>>>(
                    pbf, vt, nullptr, nullptr, abf, WS, WS, WS, WD,
                    0, (long)WD * WS, (long)WS * WD, sc_out, b, Lp);
            }
        }

        // ffh = relu(attn @ W1 + b1)   (N=64 -> old 64x64 kernel)
        gemm_k<4, true><<<dim3(WHID / 64, M / 64, 1), 256, 0, stream>>>(
            abf, w1b, b1, nullptr, fhbf, M, WHID, WD, WD, WHID, WHID, 0, 0, 0, 1.0f, 0);
        // ff = ffh @ W2 + b2  (fp32, into d_out as scratch)
        gemm8_k<5><<<dim3(WD / 128, M / 128, 1), 512, 0, stream>>>(
            fhbf, w2t, b2, out, nullptr, WHID, WHID, WHID, WD, 0, 0, 0, 1.0f, 0, nullptr);
        // h = LN2(LN1(h + ff)); last layer also writes d_out
        ln_k<<<M, 256, 0, stream>>>(h, out, g1, lb1, g2, lb2, hbf,
                                    (l == NLAYER - 1) ? out : nullptr);
    }
}

// Round 7
// 714.895 us; speedup vs baseline: 1.2628x; 1.0578x over previous
//
#include <hip/hip_runtime.h>
#include <hip/hip_bf16.h>
#include <math.h>

#define WB 4
#define WS 2048
#define WD 512
#define WHID 64
#define NLAYER 6

typedef __attribute__((ext_vector_type(8))) short short8;
typedef __attribute__((ext_vector_type(4))) short short4v;
typedef __attribute__((ext_vector_type(4))) float floatx4;

__device__ __forceinline__ short f2bf(float f) {
    union { float f; unsigned u; } x; x.f = f;
    unsigned r = (x.u + 0x7fffu + ((x.u >> 16) & 1u)) >> 16;
    return (short)r;
}

__device__ __forceinline__ void gl_lds16(const short* g, short* l) {
    __builtin_amdgcn_global_load_lds(
        (const __attribute__((address_space(1))) unsigned*)g,
        (__attribute__((address_space(3))) unsigned*)l, 16, 0, 0);
}

// bijective XCD-aware block swizzle: hw block id -> work id so that
// consecutive WORK ids land on the SAME XCD (panel reuse in one L2).
__device__ __forceinline__ void xcd_swz(int& bx, int& by, int& bz) {
    int gx = gridDim.x, gy = gridDim.y;
    int nwg = gx * gy * gridDim.z;
    int wg = blockIdx.x + gx * (blockIdx.y + gy * blockIdx.z);
    int swz = (wg & 7) * (nwg >> 3) + (wg >> 3);
    bx = swz % gx;
    int t = swz / gx;
    by = t % gy;
    bz = t / gy;
}

__device__ __forceinline__ float block_reduce(float v, bool is_max) {
    __shared__ float tmp[4];
    int lane = threadIdx.x & 63, w = threadIdx.x >> 6;
#pragma unroll
    for (int off = 32; off; off >>= 1) {
        float o = __shfl_xor(v, off);
        v = is_max ? fmaxf(v, o) : v + o;
    }
    __syncthreads();
    if (lane == 0) tmp[w] = v;
    __syncthreads();
    int nw = blockDim.x >> 6;
    float r = tmp[0];
    for (int i = 1; i < nw; i++) r = is_max ? fmaxf(r, tmp[i]) : r + tmp[i];
    return r;
}

// ---------- 256x256 NT GEMM for QK: 8 waves (2Mx4N, 128x64/wave), BK=64 ----------
// A: [M][K]=q, B: [N][K]=k. Writes P=exp(acc) bf16 + 32 row-sum partials into Lp.
// LDS: row r, 16B-block b holds global block (b ^ (r&7)); linear dest,
// swizzle via inverse-permuted per-lane global source. Zero bank conflicts.
__global__ __launch_bounds__(512) void gemm256_k(
    const short* __restrict__ A, const short* __restrict__ Bm,
    short* __restrict__ Cb, int K, int lda, int ldb, int ldc,
    long sA, long sB, long sC, int b0, float* __restrict__ Lp)
{
    __shared__ __align__(16) short As[2][256 * 64];
    __shared__ __align__(16) short Bs[2][256 * 64];
    int bx, by, bz0;
    xcd_swz(bx, by, bz0);
    int bz = b0 + bz0;
    int tid = threadIdx.x;
    int m0 = by * 256, n0 = bx * 256;
    const short* Ab = A + (long)bz * sA + (long)m0 * lda;
    const short* Bb = Bm + (long)bz * sB + (long)n0 * ldb;
    long coff = (long)bz * sC;

    int lane = tid & 63, w = tid >> 6;
    int wm = (w >> 2) * 128, wn = (w & 3) * 64;

    floatx4 acc[8][4];
#pragma unroll
    for (int mi = 0; mi < 8; mi++)
#pragma unroll
        for (int ni = 0; ni < 4; ni++) acc[mi][ni] = (floatx4){0.f, 0.f, 0.f, 0.f};

    // staging: per issue q, thread covers row q*64 + (tid>>3), 16B-block tid&7
    int sr = tid >> 3;
    int scb = (tid & 7) ^ (sr & 7);
    const short* ga0 = Ab + (long)sr * lda + scb * 8;
    const short* gb0 = Bb + (long)sr * ldb + scb * 8;
    long lda64 = (long)64 * lda, ldb64 = (long)64 * ldb;

    int arow = wm + (lane & 15);
    int brow = wn + (lane & 15);
    int a7 = arow & 7, b7 = brow & 7;
    int kb = lane >> 4;
    int aoff0 = arow * 64 + ((kb ^ a7) * 8);
    int aoff1 = arow * 64 + (((kb + 4) ^ a7) * 8);
    int boff0 = brow * 64 + ((kb ^ b7) * 8);
    int boff1 = brow * 64 + (((kb + 4) ^ b7) * 8);

    int nt = K >> 6;

    auto stage = [&](int t, int b) {
        const short* ga = ga0 + t * 64;
        const short* gb = gb0 + t * 64;
#pragma unroll
        for (int q = 0; q < 4; q++)
            gl_lds16(ga + (long)q * lda64, &As[b][q * 4096 + tid * 8]);
#pragma unroll
        for (int q = 0; q < 4; q++)
            gl_lds16(gb + (long)q * ldb64, &Bs[b][q * 4096 + tid * 8]);
    };

    stage(0, 0);

    for (int t = 0; t < nt; t++) {
        int cur = t & 1;
        if (t + 1 < nt) {
            stage(t + 1, cur ^ 1);
            asm volatile("s_waitcnt vmcnt(8)" ::: "memory");
        } else {
            asm volatile("s_waitcnt vmcnt(0)" ::: "memory");
        }
        __builtin_amdgcn_s_barrier();
        __builtin_amdgcn_sched_barrier(0);
        const short* as = As[cur];
        const short* bs = Bs[cur];
        short8 av[8], bv[4];
#pragma unroll
        for (int i = 0; i < 8; i++) av[i] = *(const short8*)&as[aoff0 + i * 1024];
#pragma unroll
        for (int i = 0; i < 4; i++) bv[i] = *(const short8*)&bs[boff0 + i * 1024];
#pragma unroll
        for (int mi = 0; mi < 8; mi++)
#pragma unroll
            for (int ni = 0; ni < 4; ni++)
                acc[mi][ni] = __builtin_amdgcn_mfma_f32_16x16x32_bf16(av[mi], bv[ni], acc[mi][ni], 0, 0, 0);
#pragma unroll
        for (int i = 0; i < 8; i++) av[i] = *(const short8*)&as[aoff1 + i * 1024];
#pragma unroll
        for (int i = 0; i < 4; i++) bv[i] = *(const short8*)&bs[boff1 + i * 1024];
#pragma unroll
        for (int mi = 0; mi < 8; mi++)
#pragma unroll
            for (int ni = 0; ni < 4; ni++)
                acc[mi][ni] = __builtin_amdgcn_mfma_f32_16x16x32_bf16(av[mi], bv[ni], acc[mi][ni], 0, 0, 0);
        __builtin_amdgcn_sched_barrier(0);
        __builtin_amdgcn_s_barrier();
    }

    int rl = (lane >> 4) * 4, col = lane & 15;
    float s_[8][4];
#pragma unroll
    for (int mi = 0; mi < 8; mi++)
#pragma unroll
        for (int j = 0; j < 4; j++) s_[mi][j] = 0.f;
#pragma unroll
    for (int mi = 0; mi < 8; mi++)
#pragma unroll
        for (int ni = 0; ni < 4; ni++) {
            int n = n0 + wn + ni * 16 + col;
            int r = wm + mi * 16 + rl;
#pragma unroll
            for (int j = 0; j < 4; j++) {
                float e = __expf(acc[mi][ni][j]);
                Cb[coff + (long)(m0 + r + j) * ldc + n] = f2bf(e);
                s_[mi][j] += e;
            }
        }
#pragma unroll
    for (int off = 1; off < 16; off <<= 1)
#pragma unroll
        for (int mi = 0; mi < 8; mi++)
#pragma unroll
            for (int j = 0; j < 4; j++) s_[mi][j] += __shfl_xor(s_[mi][j], off);
    // 32 partials per row: p = bx*4 + wave-col
    int g = lane >> 4, li = lane & 15;
    long lpb = ((long)bz * 32 + bx * 4 + (w & 3)) * WS + m0 + wm + g * 4;
#pragma unroll
    for (int hv = 0; hv < 2; hv++) {
        int idx = li + hv * 16;
        int mi = idx >> 2, j = idx & 3;
        Lp[lpb + mi * 16 + j] = s_[mi][j];
    }
}

// ---------- 128x128 NT GEMM, 8 waves, BK=64, 2-buffer counted-vmcnt pipeline ----------
// EPI: 0 = bf16 ((acc+bias)*scale); 1 = bf16 transposed into vt[B][D][S] (+bias);
//      5 = f32 (+bias); 7 = PV: bf16 acc * (scale / l[row]) with l reduced from Lp (32 partials).
template<int EPI>
__global__ __launch_bounds__(512) void gemm8_k(
    const short* __restrict__ A, const short* __restrict__ Bm,
    const float* __restrict__ bias, float* __restrict__ Cf, short* __restrict__ Cb,
    int K, int lda, int ldb, int ldc,
    long sA, long sB, long sC, float scale, int b0, float* __restrict__ Lp)
{
    __shared__ __align__(16) short As[2][128 * 64];
    __shared__ __align__(16) short Bs[2][128 * 64];
    __shared__ float lds_l[128];
    int bx, by, bz0;
    xcd_swz(bx, by, bz0);
    int tid = threadIdx.x;
    int bz = b0 + bz0;
    int m0 = by * 128, n0 = bx * 128;
    const short* Ab = A + (long)bz * sA + (long)m0 * lda;
    const short* Bb = Bm + (long)bz * sB + (long)n0 * ldb;
    long coff = (long)bz * sC;

    if (EPI == 7 && tid < 128) {
        float s = 0.f;
        const float* lp = Lp + (long)bz * 32 * WS + m0 + tid;
#pragma unroll 8
        for (int p2 = 0; p2 < 32; p2++) s += lp[(long)p2 * WS];
        lds_l[tid] = scale / s;
    }

    int lane = tid & 63, w = tid >> 6;
    int wm = (w >> 2) * 64, wn = (w & 3) * 32;

    floatx4 acc[4][2];
#pragma unroll
    for (int mi = 0; mi < 4; mi++)
#pragma unroll
        for (int ni = 0; ni < 2; ni++) acc[mi][ni] = (floatx4){0.f, 0.f, 0.f, 0.f};

    int r0 = tid >> 3;
    int sblk = (tid & 7) ^ (r0 & 7);
    const short* ga0 = Ab + (long)r0 * lda + sblk * 8;
    const short* gb0 = Bb + (long)r0 * ldb + sblk * 8;
    long lda64 = (long)64 * lda, ldb64 = (long)64 * ldb;

    int arow = wm + (lane & 15);
    int brow = wn + (lane & 15);
    int a7 = arow & 7, b7 = brow & 7;
    int kb = lane >> 4;
    int aoff0 = arow * 64 + ((kb ^ a7) * 8);
    int aoff1 = arow * 64 + (((kb + 4) ^ a7) * 8);
    int boff0 = brow * 64 + ((kb ^ b7) * 8);
    int boff1 = brow * 64 + (((kb + 4) ^ b7) * 8);

    int nt = K >> 6;

    auto stage = [&](int t, int b) {
        const short* ga = ga0 + t * 64;
        const short* gb = gb0 + t * 64;
        gl_lds16(ga, &As[b][tid * 8]);
        gl_lds16(ga + lda64, &As[b][(tid + 512) * 8]);
        gl_lds16(gb, &Bs[b][tid * 8]);
        gl_lds16(gb + ldb64, &Bs[b][(tid + 512) * 8]);
    };

    stage(0, 0);

    for (int t = 0; t < nt; t++) {
        int cur = t & 1;
        if (t + 1 < nt) {
            stage(t + 1, cur ^ 1);
            asm volatile("s_waitcnt vmcnt(4)" ::: "memory");
        } else {
            asm volatile("s_waitcnt vmcnt(0)" ::: "memory");
        }
        __builtin_amdgcn_s_barrier();
        __builtin_amdgcn_sched_barrier(0);
        const short* as = As[cur];
        const short* bs = Bs[cur];
        short8 av[4], bv[2];
#pragma unroll
        for (int i = 0; i < 4; i++) av[i] = *(const short8*)&as[aoff0 + i * 16 * 64];
#pragma unroll
        for (int i = 0; i < 2; i++) bv[i] = *(const short8*)&bs[boff0 + i * 16 * 64];
#pragma unroll
        for (int mi = 0; mi < 4; mi++)
#pragma unroll
            for (int ni = 0; ni < 2; ni++)
                acc[mi][ni] = __builtin_amdgcn_mfma_f32_16x16x32_bf16(av[mi], bv[ni], acc[mi][ni], 0, 0, 0);
#pragma unroll
        for (int i = 0; i < 4; i++) av[i] = *(const short8*)&as[aoff1 + i * 16 * 64];
#pragma unroll
        for (int i = 0; i < 2; i++) bv[i] = *(const short8*)&bs[boff1 + i * 16 * 64];
#pragma unroll
        for (int mi = 0; mi < 4; mi++)
#pragma unroll
            for (int ni = 0; ni < 2; ni++)
                acc[mi][ni] = __builtin_amdgcn_mfma_f32_16x16x32_bf16(av[mi], bv[ni], acc[mi][ni], 0, 0, 0);
        __builtin_amdgcn_sched_barrier(0);
        __builtin_amdgcn_s_barrier();
    }

    int rl = (lane >> 4) * 4, col = lane & 15;

#pragma unroll
    for (int mi = 0; mi < 4; mi++) {
#pragma unroll
        for (int ni = 0; ni < 2; ni++) {
            int n = n0 + wn + ni * 16 + col;
            float bvv = (EPI == 0 || EPI == 1 || EPI == 5) ? bias[n] : 0.f;
            if (EPI == 1) {
                int m = m0 + wm + mi * 16 + rl;
                short4v o;
#pragma unroll
                for (int j = 0; j < 4; j++) o[j] = f2bf(acc[mi][ni][j] + bvv);
                *(short4v*)&Cb[((long)(m >> 11) * WD + n) * WS + (m & (WS - 1))] = o;
            } else {
#pragma unroll
                for (int j = 0; j < 4; j++) {
                    int r = wm + mi * 16 + rl + j;
                    if (EPI == 7) {
                        float v = acc[mi][ni][j] * lds_l[r];
                        Cb[coff + (long)(m0 + r) * ldc + n] = f2bf(v);
                    } else {
                        float v = (acc[mi][ni][j] + bvv) * scale;
                        if (EPI == 5) Cf[coff + (long)(m0 + r) * ldc + n] = v;
                        else Cb[coff + (long)(m0 + r) * ldc + n] = f2bf(v);
                    }
                }
            }
        }
    }
}

// ---------------- old 64x64 GEMM, kept for FFN1 (N=64) ----------------
template<int EPI, bool BT>
__global__ __launch_bounds__(256) void gemm_k(
    const short* __restrict__ A, const short* __restrict__ Bm,
    const float* __restrict__ bias, float* __restrict__ Cf, short* __restrict__ Cb,
    int M, int N, int K, int lda, int ldb, int ldc,
    long sA, long sB, long sC, float scale, int b0)
{
    __shared__ short As[64][40];
    __shared__ short Bs[64][40];
    int bx, by, bz0;
    xcd_swz(bx, by, bz0);
    int tid = threadIdx.x;
    int bz = b0 + bz0;
    const short* Ab = A + (long)bz * sA;
    const short* Bb = Bm + (long)bz * sB;
    long coff = (long)bz * sC;
    int m0 = by * 64, n0 = bx * 64;

    floatx4 acc[4];
#pragma unroll
    for (int c = 0; c < 4; c++) acc[c] = (floatx4){0.f, 0.f, 0.f, 0.f};

    int lane = tid & 63, w = tid >> 6;
    int arow = w * 16 + (lane & 15);
    int koff = (lane >> 4) * 8;

    for (int kt = 0; kt < K; kt += 32) {
        {
            int r = tid >> 2, kc = (tid & 3) * 8;
            short8 av = *(const short8*)(Ab + (long)(m0 + r) * lda + kt + kc);
            *(short8*)&As[r][kc] = av;
        }
        if (BT) {
            int kk = tid >> 3, nn = (tid & 7) * 8;
            short8 bv = *(const short8*)(Bb + (long)(kt + kk) * ldb + n0 + nn);
#pragma unroll
            for (int e = 0; e < 8; e++) Bs[nn + e][kk] = bv[e];
        } else {
            int r = tid >> 2, kc = (tid & 3) * 8;
            short8 bv = *(const short8*)(Bb + (long)(n0 + r) * ldb + kt + kc);
            *(short8*)&Bs[r][kc] = bv;
        }
        __syncthreads();
        short8 a = *(const short8*)&As[arow][koff];
#pragma unroll
        for (int c = 0; c < 4; c++) {
            short8 b = *(const short8*)&Bs[c * 16 + (lane & 15)][koff];
            acc[c] = __builtin_amdgcn_mfma_f32_16x16x32_bf16(a, b, acc[c], 0, 0, 0);
        }
        __syncthreads();
    }

    int rl = (lane >> 4) * 4, col = lane & 15;
    int mb = m0 + w * 16 + rl;
#pragma unroll
    for (int c = 0; c < 4; c++) {
        int n = n0 + c * 16 + col;
        float bvv = (EPI == 0 || EPI == 4 || EPI == 5) ? bias[n] : 0.f;
#pragma unroll
        for (int j = 0; j < 4; j++) {
            int m = mb + j;
            float v = acc[c][j] + bvv;
            if (EPI == 4) v = fmaxf(v, 0.f);
            v *= scale;
            if (EPI == 2 || EPI == 5) {
                Cf[coff + (long)m * ldc + n] = v;
            } else {
                Cb[coff + (long)m * ldc + n] = f2bf(v);
            }
        }
    }
}

__global__ __launch_bounds__(256) void ln_k(float* __restrict__ h,
                                            const float* __restrict__ ff,
                                            const float* __restrict__ g1, const float* __restrict__ bb1,
                                            const float* __restrict__ g2, const float* __restrict__ bb2,
                                            short* __restrict__ hbf,
                                            float* __restrict__ outp)
{
    long r = blockIdx.x;
    int i = threadIdx.x;
    float2 hv = *(const float2*)&h[r * WD + i * 2];
    float2 fv = *(const float2*)&ff[r * WD + i * 2];
    float a = hv.x + fv.x, b = hv.y + fv.y;
    float mu = block_reduce(a + b, false) * (1.f / WD);
    float da = a - mu, db = b - mu;
    float var = block_reduce(da * da + db * db, false) * (1.f / WD);
    float rs = rsqrtf(var + 1e-5f);
    float y0 = da * rs * g1[2 * i] + bb1[2 * i];
    float y1 = db * rs * g1[2 * i + 1] + bb1[2 * i + 1];
    float mu2 = block_reduce(y0 + y1, false) * (1.f / WD);
    float d0 = y0 - mu2, d1 = y1 - mu2;
    float var2 = block_reduce(d0 * d0 + d1 * d1, false) * (1.f / WD);
    float rs2 = rsqrtf(var2 + 1e-5f);
    float z0 = d0 * rs2 * g2[2 * i] + bb2[2 * i];
    float z1 = d1 * rs2 * g2[2 * i + 1] + bb2[2 * i + 1];
    *(float2*)&h[r * WD + i * 2] = make_float2(z0, z1);
    hbf[r * WD + i * 2] = f2bf(z0);
    hbf[r * WD + i * 2 + 1] = f2bf(z1);
    if (outp) *(float2*)&outp[r * WD + i * 2] = make_float2(z0, z1);
}

__global__ void conv_x_k(const float* __restrict__ x, float* __restrict__ h,
                         short* __restrict__ hbf, int n4)
{
    int i = blockIdx.x * blockDim.x + threadIdx.x;
    for (; i < n4; i += gridDim.x * blockDim.x) {
        float4 v = ((const float4*)x)[i];
        ((float4*)h)[i] = v;
        short4v o;
        o[0] = f2bf(v.x); o[1] = f2bf(v.y); o[2] = f2bf(v.z); o[3] = f2bf(v.w);
        *(short4v*)&hbf[i * 4] = o;
    }
}

__global__ void conv_w_k(const float* __restrict__ x, short* __restrict__ w, int n4)
{
    int i = blockIdx.x * blockDim.x + threadIdx.x;
    for (; i < n4; i += gridDim.x * blockDim.x) {
        float4 v = ((const float4*)x)[i];
        short4v o;
        o[0] = f2bf(v.x); o[1] = f2bf(v.y); o[2] = f2bf(v.z); o[3] = f2bf(v.w);
        *(short4v*)&w[i * 4] = o;
    }
}

// W [R][C] f32 -> Wt [C][R] bf16
__global__ __launch_bounds__(256) void transpose_w_k(const float* __restrict__ W,
                                                     short* __restrict__ Wt, int R, int C)
{
    __shared__ short t[32][33];
    int c0 = blockIdx.x * 32, r0 = blockIdx.y * 32;
    int tx = threadIdx.x & 31, ty = threadIdx.x >> 5; // 32x8
#pragma unroll
    for (int i = 0; i < 32; i += 8)
        t[ty + i][tx] = f2bf(W[(long)(r0 + ty + i) * C + c0 + tx]);
    __syncthreads();
#pragma unroll
    for (int i = 0; i < 32; i += 8)
        Wt[(long)(c0 + ty + i) * R + r0 + tx] = t[tx][ty + i];
}

extern "C" void kernel_launch(void* const* d_in, const int* in_sizes, int n_in,
                              void* d_out, int out_size, void* d_ws, size_t ws_size,
                              hipStream_t stream)
{
    const float* x   = (const float*)d_in[0];
    const float* Wq  = (const float*)d_in[1];
    const float* bq  = (const float*)d_in[2];
    const float* Wk  = (const float*)d_in[3];
    const float* bk  = (const float*)d_in[4];
    const float* Wv  = (const float*)d_in[5];
    const float* bv  = (const float*)d_in[6];
    const float* W1  = (const float*)d_in[7];
    const float* b1  = (const float*)d_in[8];
    const float* W2  = (const float*)d_in[9];
    const float* b2  = (const float*)d_in[10];
    const float* g1  = (const float*)d_in[11];
    const float* lb1 = (const float*)d_in[12];
    const float* g2  = (const float*)d_in[13];
    const float* lb2 = (const float*)d_in[14];
    float* out = (float*)d_out;

    char* p = (char*)d_ws;
    auto carve = [&](size_t bytes) -> char* {
        char* r = p;
        p += (bytes + 255) & ~(size_t)255;
        return r;
    };
    float* h    = (float*)carve((size_t)WB * WS * WD * 4);
    short* hbf  = (short*)carve((size_t)WB * WS * WD * 2);
    short* kbf  = (short*)carve((size_t)WB * WS * WD * 2);
    short* vt   = (short*)carve((size_t)WB * WS * WD * 2);
    short* qbf  = (short*)carve((size_t)WB * WS * WD * 2);
    short* abf  = (short*)carve((size_t)WB * WS * WD * 2);
    short* fhbf = (short*)carve((size_t)WB * WS * WHID * 2);
    short* wqt  = (short*)carve((size_t)WD * WD * 2);
    short* wkt  = (short*)carve((size_t)WD * WD * 2);
    short* wvt  = (short*)carve((size_t)WD * WD * 2);
    short* w1b  = (short*)carve((size_t)WD * WHID * 2);
    short* w2t  = (short*)carve((size_t)WHID * WD * 2);
    float* Lp   = (float*)carve((size_t)WB * 32 * WS * 4);
    size_t used_base = (size_t)(p - (char*)d_ws);
    size_t full_extra = (size_t)WB * WS * WS * 2 + 1024;
    bool full = ws_size >= used_base + full_extra;
    short* pbf;
    if (full) {
        pbf = (short*)carve((size_t)WB * WS * WS * 2);
    } else {
        pbf = (short*)carve((size_t)WS * WS * 2);
    }

    const int M = WB * WS;
    const float sc_attn = 0.125f;           // 1/sqrt(HID=64), folded into Q proj (exact pow2)
    const float sc_out  = 0.04419417382f;   // 1/sqrt(D=512)

    conv_x_k<<<2048, 256, 0, stream>>>(x, h, hbf, WB * WS * WD / 4);
    transpose_w_k<<<dim3(WD / 32, WD / 32), 256, 0, stream>>>(Wq, wqt, WD, WD);
    transpose_w_k<<<dim3(WD / 32, WD / 32), 256, 0, stream>>>(Wk, wkt, WD, WD);
    transpose_w_k<<<dim3(WD / 32, WD / 32), 256, 0, stream>>>(Wv, wvt, WD, WD);
    transpose_w_k<<<dim3(WD / 32, WHID / 32), 256, 0, stream>>>(W2, w2t, WHID, WD);
    conv_w_k<<<64, 256, 0, stream>>>(W1, w1b, WD * WHID / 4);

    // k = x @ Wk + bk  (bf16, row-major [B*S][D])
    gemm8_k<0><<<dim3(WD / 128, M / 128, 1), 512, 0, stream>>>(
        hbf, wkt, bk, nullptr, kbf, WD, WD, WD, WD, 0, 0, 0, 1.0f, 0, nullptr);
    // v = x @ Wv + bv  (bf16, transposed per batch: [B][D][S])
    gemm8_k<1><<<dim3(WD / 128, M / 128, 1), 512, 0, stream>>>(
        hbf, wvt, bv, nullptr, vt, WD, WD, WD, WD, 0, 0, 0, 1.0f, 0, nullptr);

    for (int l = 0; l < NLAYER; l++) {
        // q = (h @ Wq + bq) * sc_attn
        gemm8_k<0><<<dim3(WD / 128, M / 128, 1), 512, 0, stream>>>(
            hbf, wqt, bq, nullptr, qbf, WD, WD, WD, WD, 0, 0, 0, sc_attn, 0, nullptr);

        if (full) {
            // P = exp(q @ k^T), 32 row-sum partials -> Lp  (256^2 tile)
            gemm256_k<<<dim3(WS / 256, WS / 256, WB), 512, 0, stream>>>(
                qbf, kbf, pbf, WD, WD, WD, WS,
                (long)WS * WD, (long)WS * WD, (long)WS * WS, 0, Lp);
            // attn = (P @ V) * sc_out / l
            gemm8_k<7><<<dim3(WD / 128, WS / 128, WB), 512, 0, stream>>>(
                pbf, vt, nullptr, nullptr, abf, WS, WS, WS, WD,
                (long)WS * WS, (long)WD * WS, (long)WS * WD, sc_out, 0, Lp);
        } else {
            for (int b = 0; b < WB; b++) {
                gemm256_k<<<dim3(WS / 256, WS / 256, 1), 512, 0, stream>>>(
                    qbf, kbf, pbf, WD, WD, WD, WS,
                    (long)WS * WD, (long)WS * WD, 0, b, Lp);
                gemm8_k<7><<<dim3(WD / 128, WS / 128, 1), 512, 0, stream>>>(
                    pbf, vt, nullptr, nullptr, abf, WS, WS, WS, WD,
                    0, (long)WD * WS, (long)WS * WD, sc_out, b, Lp);
            }
        }

        // ffh = relu(attn @ W1 + b1)   (N=64 -> old 64x64 kernel)
        gemm_k<4, true><<<dim3(WHID / 64, M / 64, 1), 256, 0, stream>>>(
            abf, w1b, b1, nullptr, fhbf, M, WHID, WD, WD, WHID, WHID, 0, 0, 0, 1.0f, 0);
        // ff = ffh @ W2 + b2  (fp32, into d_out as scratch)
        gemm8_k<5><<<dim3(WD / 128, M / 128, 1), 512, 0, stream>>>(
            fhbf, w2t, b2, out, nullptr, WHID, WHID, WHID, WD, 0, 0, 0, 1.0f, 0, nullptr);
        // h = LN2(LN1(h + ff)); last layer also writes d_out
        ln_k<<<M, 256, 0, stream>>>(h, out, g1, lb1, g2, lb2, hbf,
                                    (l == NLAYER - 1) ? out : nullptr);
    }
}

// Round 9
// 504.100 us; speedup vs baseline: 1.7909x; 1.4182x over previous
//
#include <hip/hip_runtime.h>
#include <hip/hip_bf16.h>
#include <math.h>

#define WB 4
#define WS 2048
#define WD 512
#define WHID 64
#define NLAYER 6

typedef __attribute__((ext_vector_type(8))) short short8;
typedef __attribute__((ext_vector_type(4))) short short4v;
typedef __attribute__((ext_vector_type(4))) float floatx4;

__device__ __forceinline__ short f2bf(float f) {
    union { float f; unsigned u; } x; x.f = f;
    unsigned r = (x.u + 0x7fffu + ((x.u >> 16) & 1u)) >> 16;
    return (short)r;
}

__device__ __forceinline__ float bf2f(short s) {
    union { unsigned u; float f; } c;
    c.u = ((unsigned)(unsigned short)s) << 16;
    return c.f;
}

__device__ __forceinline__ void gl_lds16(const short* g, short* l) {
    __builtin_amdgcn_global_load_lds(
        (const __attribute__((address_space(1))) unsigned*)g,
        (__attribute__((address_space(3))) unsigned*)l, 16, 0, 0);
}

// bijective XCD-aware block swizzle (nwg % 8 == 0): consecutive WORK ids -> same XCD
__device__ __forceinline__ void xcd_swz(int& bx, int& by, int& bz) {
    int gx = gridDim.x, gy = gridDim.y;
    int nwg = gx * gy * gridDim.z;
    int wg = blockIdx.x + gx * (blockIdx.y + gy * blockIdx.z);
    int swz = (wg & 7) * (nwg >> 3) + (wg >> 3);
    bx = swz % gx;
    int t = swz / gx;
    by = t % gy;
    bz = t / gy;
}

__device__ __forceinline__ float block_reduce(float v, bool is_max) {
    __shared__ float tmp[4];
    int lane = threadIdx.x & 63, w = threadIdx.x >> 6;
#pragma unroll
    for (int off = 32; off; off >>= 1) {
        float o = __shfl_xor(v, off);
        v = is_max ? fmaxf(v, o) : v + o;
    }
    __syncthreads();
    if (lane == 0) tmp[w] = v;
    __syncthreads();
    int nw = blockDim.x >> 6;
    float r = tmp[0];
    for (int i = 1; i < nw; i++) r = is_max ? fmaxf(r, tmp[i]) : r + tmp[i];
    return r;
}

// ---------- 256x256 NT GEMM for QK': P = exp(h@G + rq), row-sum partials -> Lp ----------
__global__ __launch_bounds__(512) void gemm256_k(
    const short* __restrict__ A, const short* __restrict__ Bm,
    short* __restrict__ Cb, int K, int lda, int ldb, int ldc,
    long sA, long sB, long sC, int b0, float* __restrict__ Lp,
    const float* __restrict__ rq)
{
    __shared__ __align__(16) short As[2][256 * 64];
    __shared__ __align__(16) short Bs[2][256 * 64];
    int bx, by, bz0;
    xcd_swz(bx, by, bz0);
    int bz = b0 + bz0;
    int tid = threadIdx.x;
    int m0 = by * 256, n0 = bx * 256;
    const short* Ab = A + (long)bz * sA + (long)m0 * lda;
    const short* Bb = Bm + (long)bz * sB + (long)n0 * ldb;
    long coff = (long)bz * sC;

    int lane = tid & 63, w = tid >> 6;
    int wm = (w >> 2) * 128, wn = (w & 3) * 64;

    floatx4 acc[8][4];
#pragma unroll
    for (int mi = 0; mi < 8; mi++)
#pragma unroll
        for (int ni = 0; ni < 4; ni++) acc[mi][ni] = (floatx4){0.f, 0.f, 0.f, 0.f};

    int sr = tid >> 3;
    int scb = (tid & 7) ^ (sr & 7);
    const short* ga0 = Ab + (long)sr * lda + scb * 8;
    const short* gb0 = Bb + (long)sr * ldb + scb * 8;
    long lda64 = (long)64 * lda, ldb64 = (long)64 * ldb;

    int arow = wm + (lane & 15);
    int brow = wn + (lane & 15);
    int a7 = arow & 7, b7 = brow & 7;
    int kb = lane >> 4;
    int aoff0 = arow * 64 + ((kb ^ a7) * 8);
    int aoff1 = arow * 64 + (((kb + 4) ^ a7) * 8);
    int boff0 = brow * 64 + ((kb ^ b7) * 8);
    int boff1 = brow * 64 + (((kb + 4) ^ b7) * 8);

    int nt = K >> 6;

    auto stage = [&](int t, int b) {
        const short* ga = ga0 + t * 64;
        const short* gb = gb0 + t * 64;
#pragma unroll
        for (int q = 0; q < 4; q++)
            gl_lds16(ga + (long)q * lda64, &As[b][q * 4096 + tid * 8]);
#pragma unroll
        for (int q = 0; q < 4; q++)
            gl_lds16(gb + (long)q * ldb64, &Bs[b][q * 4096 + tid * 8]);
    };

    stage(0, 0);

    for (int t = 0; t < nt; t++) {
        int cur = t & 1;
        if (t + 1 < nt) {
            stage(t + 1, cur ^ 1);
            asm volatile("s_waitcnt vmcnt(8)" ::: "memory");
        } else {
            asm volatile("s_waitcnt vmcnt(0)" ::: "memory");
        }
        __builtin_amdgcn_s_barrier();
        __builtin_amdgcn_sched_barrier(0);
        const short* as = As[cur];
        const short* bs = Bs[cur];
        short8 av[8], bv[4];
#pragma unroll
        for (int i = 0; i < 8; i++) av[i] = *(const short8*)&as[aoff0 + i * 1024];
#pragma unroll
        for (int i = 0; i < 4; i++) bv[i] = *(const short8*)&bs[boff0 + i * 1024];
#pragma unroll
        for (int mi = 0; mi < 8; mi++)
#pragma unroll
            for (int ni = 0; ni < 4; ni++)
                acc[mi][ni] = __builtin_amdgcn_mfma_f32_16x16x32_bf16(av[mi], bv[ni], acc[mi][ni], 0, 0, 0);
#pragma unroll
        for (int i = 0; i < 8; i++) av[i] = *(const short8*)&as[aoff1 + i * 1024];
#pragma unroll
        for (int i = 0; i < 4; i++) bv[i] = *(const short8*)&bs[boff1 + i * 1024];
#pragma unroll
        for (int mi = 0; mi < 8; mi++)
#pragma unroll
            for (int ni = 0; ni < 4; ni++)
                acc[mi][ni] = __builtin_amdgcn_mfma_f32_16x16x32_bf16(av[mi], bv[ni], acc[mi][ni], 0, 0, 0);
        __builtin_amdgcn_sched_barrier(0);
        __builtin_amdgcn_s_barrier();
    }

    int rl = (lane >> 4) * 4, col = lane & 15;
    float s_[8][4];
#pragma unroll
    for (int mi = 0; mi < 8; mi++)
#pragma unroll
        for (int j = 0; j < 4; j++) s_[mi][j] = 0.f;
#pragma unroll
    for (int ni = 0; ni < 4; ni++) {
        int n = n0 + wn + ni * 16 + col;
        float rv = rq[(long)bz * WS + n];
#pragma unroll
        for (int mi = 0; mi < 8; mi++) {
            int r = wm + mi * 16 + rl;
#pragma unroll
            for (int j = 0; j < 4; j++) {
                float e = __expf(acc[mi][ni][j] + rv);
                Cb[coff + (long)(m0 + r + j) * ldc + n] = f2bf(e);
                s_[mi][j] += e;
            }
        }
    }
#pragma unroll
    for (int off = 1; off < 16; off <<= 1)
#pragma unroll
        for (int mi = 0; mi < 8; mi++)
#pragma unroll
            for (int j = 0; j < 4; j++) s_[mi][j] += __shfl_xor(s_[mi][j], off);
    int g = lane >> 4, li = lane & 15;
    long lpb = ((long)bz * 32 + bx * 4 + (w & 3)) * WS + m0 + wm + g * 4;
#pragma unroll
    for (int hv = 0; hv < 2; hv++) {
        int idx = li + hv * 16;
        int mi = idx >> 2, j = idx & 3;
        Lp[lpb + mi * 16 + j] = s_[mi][j];
    }
}

// ---------- 128x128 NT GEMM, 8 waves, BK=64, 2-buf counted-vmcnt ----------
// EPI: 0 = bf16 ((acc+bias)*scale); 5 = f32 (+bias);
//      8 = bf16 transposed within batch: Cb[coff + n*ldc + m], *scale, no bias.
template<int EPI>
__global__ __launch_bounds__(512) void gemm8_k(
    const short* __restrict__ A, const short* __restrict__ Bm,
    const float* __restrict__ bias, float* __restrict__ Cf, short* __restrict__ Cb,
    int K, int lda, int ldb, int ldc,
    long sA, long sB, long sC, float scale, int b0)
{
    __shared__ __align__(16) short As[2][128 * 64];
    __shared__ __align__(16) short Bs[2][128 * 64];
    int bx, by, bz0;
    xcd_swz(bx, by, bz0);
    int tid = threadIdx.x;
    int bz = b0 + bz0;
    int m0 = by * 128, n0 = bx * 128;
    const short* Ab = A + (long)bz * sA + (long)m0 * lda;
    const short* Bb = Bm + (long)bz * sB + (long)n0 * ldb;
    long coff = (long)bz * sC;

    int lane = tid & 63, w = tid >> 6;
    int wm = (w >> 2) * 64, wn = (w & 3) * 32;

    floatx4 acc[4][2];
#pragma unroll
    for (int mi = 0; mi < 4; mi++)
#pragma unroll
        for (int ni = 0; ni < 2; ni++) acc[mi][ni] = (floatx4){0.f, 0.f, 0.f, 0.f};

    int r0 = tid >> 3;
    int sblk = (tid & 7) ^ (r0 & 7);
    const short* ga0 = Ab + (long)r0 * lda + sblk * 8;
    const short* gb0 = Bb + (long)r0 * ldb + sblk * 8;
    long lda64 = (long)64 * lda, ldb64 = (long)64 * ldb;

    int arow = wm + (lane & 15);
    int brow = wn + (lane & 15);
    int a7 = arow & 7, b7 = brow & 7;
    int kb = lane >> 4;
    int aoff0 = arow * 64 + ((kb ^ a7) * 8);
    int aoff1 = arow * 64 + (((kb + 4) ^ a7) * 8);
    int boff0 = brow * 64 + ((kb ^ b7) * 8);
    int boff1 = brow * 64 + (((kb + 4) ^ b7) * 8);

    int nt = K >> 6;

    auto stage = [&](int t, int b) {
        const short* ga = ga0 + t * 64;
        const short* gb = gb0 + t * 64;
        gl_lds16(ga, &As[b][tid * 8]);
        gl_lds16(ga + lda64, &As[b][(tid + 512) * 8]);
        gl_lds16(gb, &Bs[b][tid * 8]);
        gl_lds16(gb + ldb64, &Bs[b][(tid + 512) * 8]);
    };

    stage(0, 0);

    for (int t = 0; t < nt; t++) {
        int cur = t & 1;
        if (t + 1 < nt) {
            stage(t + 1, cur ^ 1);
            asm volatile("s_waitcnt vmcnt(4)" ::: "memory");
        } else {
            asm volatile("s_waitcnt vmcnt(0)" ::: "memory");
        }
        __builtin_amdgcn_s_barrier();
        __builtin_amdgcn_sched_barrier(0);
        const short* as = As[cur];
        const short* bs = Bs[cur];
        short8 av[4], bv[2];
#pragma unroll
        for (int i = 0; i < 4; i++) av[i] = *(const short8*)&as[aoff0 + i * 16 * 64];
#pragma unroll
        for (int i = 0; i < 2; i++) bv[i] = *(const short8*)&bs[boff0 + i * 16 * 64];
#pragma unroll
        for (int mi = 0; mi < 4; mi++)
#pragma unroll
            for (int ni = 0; ni < 2; ni++)
                acc[mi][ni] = __builtin_amdgcn_mfma_f32_16x16x32_bf16(av[mi], bv[ni], acc[mi][ni], 0, 0, 0);
#pragma unroll
        for (int i = 0; i < 4; i++) av[i] = *(const short8*)&as[aoff1 + i * 16 * 64];
#pragma unroll
        for (int i = 0; i < 2; i++) bv[i] = *(const short8*)&bs[boff1 + i * 16 * 64];
#pragma unroll
        for (int mi = 0; mi < 4; mi++)
#pragma unroll
            for (int ni = 0; ni < 2; ni++)
                acc[mi][ni] = __builtin_amdgcn_mfma_f32_16x16x32_bf16(av[mi], bv[ni], acc[mi][ni], 0, 0, 0);
        __builtin_amdgcn_sched_barrier(0);
        __builtin_amdgcn_s_barrier();
    }

    int rl = (lane >> 4) * 4, col = lane & 15;

#pragma unroll
    for (int mi = 0; mi < 4; mi++) {
#pragma unroll
        for (int ni = 0; ni < 2; ni++) {
            int n = n0 + wn + ni * 16 + col;
            if (EPI == 8) {
                int m = m0 + wm + mi * 16 + rl;
                short4v o;
#pragma unroll
                for (int j = 0; j < 4; j++) o[j] = f2bf(acc[mi][ni][j] * scale);
                *(short4v*)&Cb[coff + (long)n * ldc + m] = o;
            } else {
                float bvv = bias ? bias[n] : 0.f;
#pragma unroll
                for (int j = 0; j < 4; j++) {
                    int r = wm + mi * 16 + rl + j;
                    float v = (acc[mi][ni][j] + bvv) * scale;
                    if (EPI == 5) Cf[coff + (long)(m0 + r) * ldc + n] = v;
                    else Cb[coff + (long)(m0 + r) * ldc + n] = f2bf(v);
                }
            }
        }
    }
}

// ---------- PV' split-K: partial[kp] = P[:,kp*512:+512] @ VW1t^T, f32 ----------
// grid: x=kp(4), y=m-tile(16 of 128), z=batch. 8 waves, wave tile 32x32.
__global__ __launch_bounds__(512) void pv64_k(
    const short* __restrict__ P, const short* __restrict__ Vw,
    float* __restrict__ Pp, int b0, long sP)
{
    __shared__ __align__(16) short As[2][128 * 64];
    __shared__ __align__(16) short Bs[2][64 * 64];
    int kp = blockIdx.x, my = blockIdx.y;
    int bz = b0 + blockIdx.z;
    int tid = threadIdx.x;
    int m0 = my * 128;
    const short* Ab = P + (long)bz * sP + (long)m0 * WS + kp * 512;
    const short* Bb = Vw + (long)bz * WHID * WS + kp * 512;

    int lane = tid & 63, w = tid >> 6;
    int wm = (w >> 1) * 32, wn = (w & 1) * 32;

    floatx4 acc[2][2];
#pragma unroll
    for (int mi = 0; mi < 2; mi++)
#pragma unroll
        for (int ni = 0; ni < 2; ni++) acc[mi][ni] = (floatx4){0.f, 0.f, 0.f, 0.f};

    int sr = tid >> 3;
    int scb = (tid & 7) ^ (sr & 7);
    const short* ga0 = Ab + (long)sr * WS + scb * 8;
    const short* gb0 = Bb + (long)sr * WS + scb * 8;
    long lda64 = (long)64 * WS;

    int arow = wm + (lane & 15);
    int brow = wn + (lane & 15);
    int a7 = arow & 7, b7 = brow & 7;
    int kb = lane >> 4;
    int aoff0 = arow * 64 + ((kb ^ a7) * 8);
    int aoff1 = arow * 64 + (((kb + 4) ^ a7) * 8);
    int boff0 = brow * 64 + ((kb ^ b7) * 8);
    int boff1 = brow * 64 + (((kb + 4) ^ b7) * 8);

    auto stage = [&](int t, int b) {
        const short* ga = ga0 + t * 64;
        gl_lds16(ga, &As[b][tid * 8]);
        gl_lds16(ga + lda64, &As[b][(tid + 512) * 8]);
        gl_lds16(gb0 + t * 64, &Bs[b][tid * 8]);
    };

    stage(0, 0);

    for (int t = 0; t < 8; t++) {
        int cur = t & 1;
        if (t + 1 < 8) {
            stage(t + 1, cur ^ 1);
            asm volatile("s_waitcnt vmcnt(3)" ::: "memory");
        } else {
            asm volatile("s_waitcnt vmcnt(0)" ::: "memory");
        }
        __builtin_amdgcn_s_barrier();
        __builtin_amdgcn_sched_barrier(0);
        const short* as = As[cur];
        const short* bs = Bs[cur];
        short8 av[2], bv[2];
#pragma unroll
        for (int i = 0; i < 2; i++) av[i] = *(const short8*)&as[aoff0 + i * 1024];
#pragma unroll
        for (int i = 0; i < 2; i++) bv[i] = *(const short8*)&bs[boff0 + i * 1024];
#pragma unroll
        for (int mi = 0; mi < 2; mi++)
#pragma unroll
            for (int ni = 0; ni < 2; ni++)
                acc[mi][ni] = __builtin_amdgcn_mfma_f32_16x16x32_bf16(av[mi], bv[ni], acc[mi][ni], 0, 0, 0);
#pragma unroll
        for (int i = 0; i < 2; i++) av[i] = *(const short8*)&as[aoff1 + i * 1024];
#pragma unroll
        for (int i = 0; i < 2; i++) bv[i] = *(const short8*)&bs[boff1 + i * 1024];
#pragma unroll
        for (int mi = 0; mi < 2; mi++)
#pragma unroll
            for (int ni = 0; ni < 2; ni++)
                acc[mi][ni] = __builtin_amdgcn_mfma_f32_16x16x32_bf16(av[mi], bv[ni], acc[mi][ni], 0, 0, 0);
        __builtin_amdgcn_sched_barrier(0);
        __builtin_amdgcn_s_barrier();
    }

    int rl = (lane >> 4) * 4, col = lane & 15;
#pragma unroll
    for (int mi = 0; mi < 2; mi++) {
#pragma unroll
        for (int ni = 0; ni < 2; ni++) {
            int jn = wn + ni * 16 + col;
#pragma unroll
            for (int j = 0; j < 4; j++) {
                int m = m0 + wm + mi * 16 + rl + j;
                Pp[(((long)kp * WB + bz) * WS + m) * WHID + jn] = acc[mi][ni][j];
            }
        }
    }
}

// reduce: hid = relu(sc_out/l * sum_kp Pp + b1) -> fhbf bf16
__global__ __launch_bounds__(256) void ffh_red(
    const float* __restrict__ Pp, const float* __restrict__ Lp,
    const float* __restrict__ b1, short* __restrict__ fhbf, float sc)
{
    int idx = blockIdx.x * 4 + (threadIdx.x >> 6);  // row over B*S
    int j = threadIdx.x & 63;
    int b = idx >> 11, m = idx & (WS - 1);
    float l = 0.f;
    const float* lp = Lp + (long)b * 32 * WS + m;
#pragma unroll 8
    for (int p2 = 0; p2 < 32; p2++) l += lp[(long)p2 * WS];
    float s = 0.f;
#pragma unroll
    for (int kp = 0; kp < 4; kp++)
        s += Pp[(((long)kp * WB + b) * WS + m) * WHID + j];
    float v = fmaxf(s * (sc / l) + b1[j], 0.f);
    fhbf[(long)idx * WHID + j] = f2bf(v);
}

// rq[b][n] = sc_attn * dot(bq, k[b][n])
__global__ __launch_bounds__(256) void rq_k(const short* __restrict__ kbf,
                                            const float* __restrict__ bq,
                                            float* __restrict__ rq)
{
    __shared__ float sbq[WD];
    int tid = threadIdx.x;
    for (int i = tid; i < WD; i += 256) sbq[i] = bq[i];
    __syncthreads();
    int idx = blockIdx.x * 256 + tid;
    const short* kr = kbf + (long)idx * WD;
    float s = 0.f;
    for (int d = 0; d < WD; d += 8) {
        short8 kv = *(const short8*)(kr + d);
#pragma unroll
        for (int e = 0; e < 8; e++) s += bf2f(kv[e]) * sbq[d + e];
    }
    rq[idx] = s * 0.125f;
}

// ---------------- 64-tile GEMM (M<=64): C = A@B^T * scale, bf16 out ----------------
__global__ __launch_bounds__(256) void gemm_k(
    const short* __restrict__ A, const short* __restrict__ Bm,
    short* __restrict__ Cb,
    int M, int N, int K, int lda, int ldb, int ldc,
    long sA, long sB, long sC, float scale, int b0)
{
    __shared__ short As[64][40];
    __shared__ short Bs[64][40];
    int bx, by, bz0;
    xcd_swz(bx, by, bz0);
    int tid = threadIdx.x;
    int bz = b0 + bz0;
    const short* Ab = A + (long)bz * sA;
    const short* Bb = Bm + (long)bz * sB;
    long coff = (long)bz * sC;
    int m0 = by * 64, n0 = bx * 64;

    floatx4 acc[4];
#pragma unroll
    for (int c = 0; c < 4; c++) acc[c] = (floatx4){0.f, 0.f, 0.f, 0.f};

    int lane = tid & 63, w = tid >> 6;
    int arow = w * 16 + (lane & 15);
    int koff = (lane >> 4) * 8;

    for (int kt = 0; kt < K; kt += 32) {
        {
            int r = tid >> 2, kc = (tid & 3) * 8;
            int ar = m0 + r < M ? m0 + r : M - 1;
            short8 av = *(const short8*)(Ab + (long)ar * lda + kt + kc);
            *(short8*)&As[r][kc] = av;
        }
        {
            int r = tid >> 2, kc = (tid & 3) * 8;
            short8 bv = *(const short8*)(Bb + (long)(n0 + r) * ldb + kt + kc);
            *(short8*)&Bs[r][kc] = bv;
        }
        __syncthreads();
        short8 a = *(const short8*)&As[arow][koff];
#pragma unroll
        for (int c = 0; c < 4; c++) {
            short8 b = *(const short8*)&Bs[c * 16 + (lane & 15)][koff];
            acc[c] = __builtin_amdgcn_mfma_f32_16x16x32_bf16(a, b, acc[c], 0, 0, 0);
        }
        __syncthreads();
    }

    int rl = (lane >> 4) * 4, col = lane & 15;
    int mb = m0 + w * 16 + rl;
#pragma unroll
    for (int c = 0; c < 4; c++) {
        int n = n0 + c * 16 + col;
#pragma unroll
        for (int j = 0; j < 4; j++) {
            int m = mb + j;
            if (m < M) Cb[coff + (long)m * ldc + n] = f2bf(acc[c][j] * scale);
        }
    }
}

__global__ __launch_bounds__(256) void ln_k(float* __restrict__ h,
                                            const float* __restrict__ ff,
                                            const float* __restrict__ g1, const float* __restrict__ bb1,
                                            const float* __restrict__ g2, const float* __restrict__ bb2,
                                            short* __restrict__ hbf,
                                            float* __restrict__ outp)
{
    long r = blockIdx.x;
    int i = threadIdx.x;
    float2 hv = *(const float2*)&h[r * WD + i * 2];
    float2 fv = *(const float2*)&ff[r * WD + i * 2];
    float a = hv.x + fv.x, b = hv.y + fv.y;
    float mu = block_reduce(a + b, false) * (1.f / WD);
    float da = a - mu, db = b - mu;
    float var = block_reduce(da * da + db * db, false) * (1.f / WD);
    float rs = rsqrtf(var + 1e-5f);
    float y0 = da * rs * g1[2 * i] + bb1[2 * i];
    float y1 = db * rs * g1[2 * i + 1] + bb1[2 * i + 1];
    float mu2 = block_reduce(y0 + y1, false) * (1.f / WD);
    float d0 = y0 - mu2, d1 = y1 - mu2;
    float var2 = block_reduce(d0 * d0 + d1 * d1, false) * (1.f / WD);
    float rs2 = rsqrtf(var2 + 1e-5f);
    float z0 = d0 * rs2 * g2[2 * i] + bb2[2 * i];
    float z1 = d1 * rs2 * g2[2 * i + 1] + bb2[2 * i + 1];
    *(float2*)&h[r * WD + i * 2] = make_float2(z0, z1);
    hbf[r * WD + i * 2] = f2bf(z0);
    hbf[r * WD + i * 2 + 1] = f2bf(z1);
    if (outp) *(float2*)&outp[r * WD + i * 2] = make_float2(z0, z1);
}

__global__ void conv_x_k(const float* __restrict__ x, float* __restrict__ h,
                         short* __restrict__ hbf, int n4)
{
    int i = blockIdx.x * blockDim.x + threadIdx.x;
    for (; i < n4; i += gridDim.x * blockDim.x) {
        float4 v = ((const float4*)x)[i];
        ((float4*)h)[i] = v;
        short4v o;
        o[0] = f2bf(v.x); o[1] = f2bf(v.y); o[2] = f2bf(v.z); o[3] = f2bf(v.w);
        *(short4v*)&hbf[i * 4] = o;
    }
}

__global__ void conv_w_k(const float* __restrict__ x, short* __restrict__ w, int n4)
{
    int i = blockIdx.x * blockDim.x + threadIdx.x;
    for (; i < n4; i += gridDim.x * blockDim.x) {
        float4 v = ((const float4*)x)[i];
        short4v o;
        o[0] = f2bf(v.x); o[1] = f2bf(v.y); o[2] = f2bf(v.z); o[3] = f2bf(v.w);
        *(short4v*)&w[i * 4] = o;
    }
}

// W [R][C] f32 -> Wt [C][R] bf16
__global__ __launch_bounds__(256) void transpose_w_k(const float* __restrict__ W,
                                                     short* __restrict__ Wt, int R, int C)
{
    __shared__ short t[32][33];
    int c0 = blockIdx.x * 32, r0 = blockIdx.y * 32;
    int tx = threadIdx.x & 31, ty = threadIdx.x >> 5;
#pragma unroll
    for (int i = 0; i < 32; i += 8)
        t[ty + i][tx] = f2bf(W[(long)(r0 + ty + i) * C + c0 + tx]);
    __syncthreads();
#pragma unroll
    for (int i = 0; i < 32; i += 8)
        Wt[(long)(c0 + ty + i) * R + r0 + tx] = t[tx][ty + i];
}

extern "C" void kernel_launch(void* const* d_in, const int* in_sizes, int n_in,
                              void* d_out, int out_size, void* d_ws, size_t ws_size,
                              hipStream_t stream)
{
    const float* x   = (const float*)d_in[0];
    const float* Wq  = (const float*)d_in[1];
    const float* bq  = (const float*)d_in[2];
    const float* Wk  = (const float*)d_in[3];
    const float* bk  = (const float*)d_in[4];
    const float* Wv  = (const float*)d_in[5];
    const float* bv  = (const float*)d_in[6];
    const float* W1  = (const float*)d_in[7];
    const float* b1  = (const float*)d_in[8];
    const float* W2  = (const float*)d_in[9];
    const float* b2  = (const float*)d_in[10];
    const float* g1  = (const float*)d_in[11];
    const float* lb1 = (const float*)d_in[12];
    const float* g2  = (const float*)d_in[13];
    const float* lb2 = (const float*)d_in[14];
    float* out = (float*)d_out;

    char* p = (char*)d_ws;
    auto carve = [&](size_t bytes) -> char* {
        char* r = p;
        p += (bytes + 255) & ~(size_t)255;
        return r;
    };
    float* h    = (float*)carve((size_t)WB * WS * WD * 4);
    short* hbf  = (short*)carve((size_t)WB * WS * WD * 2);
    short* kbf  = (short*)carve((size_t)WB * WS * WD * 2);
    short* vbf  = (short*)carve((size_t)WB * WS * WD * 2);
    short* Gt   = (short*)carve((size_t)WB * WS * WD * 2);   // [b][n][e]
    short* vw1t = (short*)carve((size_t)WB * WHID * WS * 2); // [b][j][s]
    short* fhbf = (short*)carve((size_t)WB * WS * WHID * 2);
    short* wqb  = (short*)carve((size_t)WD * WD * 2);
    short* wkt  = (short*)carve((size_t)WD * WD * 2);
    short* wvt  = (short*)carve((size_t)WD * WD * 2);
    short* w1t  = (short*)carve((size_t)WHID * WD * 2);      // [64][512]
    short* w2t  = (short*)carve((size_t)WD * WHID * 2);      // [512][64]
    float* rq   = (float*)carve((size_t)WB * WS * 4);
    float* Lp   = (float*)carve((size_t)WB * 32 * WS * 4);
    float* Pp   = (float*)carve((size_t)4 * WB * WS * WHID * 4);
    size_t used_base = (size_t)(p - (char*)d_ws);
    size_t full_extra = (size_t)WB * WS * WS * 2 + 1024;
    bool full = ws_size >= used_base + full_extra;
    short* pbf;
    if (full) pbf = (short*)carve((size_t)WB * WS * WS * 2);
    else      pbf = (short*)carve((size_t)WS * WS * 2);

    const int M = WB * WS;
    const float sc_attn = 0.125f;
    const float sc_out  = 0.04419417382f;   // 1/sqrt(512)

    conv_x_k<<<2048, 256, 0, stream>>>(x, h, hbf, WB * WS * WD / 4);
    conv_w_k<<<256, 256, 0, stream>>>(Wq, wqb, WD * WD / 4);
    transpose_w_k<<<dim3(WD / 32, WD / 32), 256, 0, stream>>>(Wk, wkt, WD, WD);
    transpose_w_k<<<dim3(WD / 32, WD / 32), 256, 0, stream>>>(Wv, wvt, WD, WD);
    transpose_w_k<<<dim3(WHID / 32, WD / 32), 256, 0, stream>>>(W1, w1t, WD, WHID);
    transpose_w_k<<<dim3(WD / 32, WHID / 32), 256, 0, stream>>>(W2, w2t, WHID, WD);

    // k = x @ Wk + bk ; v = x @ Wv + bv   (bf16 row-major [B*S][D])
    gemm8_k<0><<<dim3(WD / 128, M / 128, 1), 512, 0, stream>>>(
        hbf, wkt, bk, nullptr, kbf, WD, WD, WD, WD, 0, 0, 0, 1.0f, 0);
    gemm8_k<0><<<dim3(WD / 128, M / 128, 1), 512, 0, stream>>>(
        hbf, wvt, bv, nullptr, vbf, WD, WD, WD, WD, 0, 0, 0, 1.0f, 0);

    // Gt[b][n][e] = sc_attn * sum_d Wq[e][d]*k[b][n][d]   (M=512 e, N=2048 n)
    gemm8_k<8><<<dim3(WS / 128, WD / 128, WB), 512, 0, stream>>>(
        wqb, kbf, nullptr, nullptr, Gt, WD, WD, WD, WD,
        0, (long)WS * WD, (long)WS * WD, sc_attn, 0);
    // rq[b][n] = sc_attn * dot(bq, k[b][n])
    rq_k<<<WB * WS / 256, 256, 0, stream>>>(kbf, bq, rq);
    // vw1t[b][j][s] = sum_d W1[d][j]*v[b][s][d]   (M=64 j, N=2048 s over 64-tiles)
    gemm_k<<<dim3(WS / 64, 1, WB), 256, 0, stream>>>(
        w1t, vbf, vw1t, WHID, WS, WD, WD, WD, WS,
        0, (long)WS * WD, (long)WHID * WS, 1.0f, 0);

    for (int l = 0; l < NLAYER; l++) {
        if (full) {
            gemm256_k<<<dim3(WS / 256, WS / 256, WB), 512, 0, stream>>>(
                hbf, Gt, pbf, WD, WD, WD, WS,
                (long)WS * WD, (long)WS * WD, (long)WS * WS, 0, Lp, rq);
            pv64_k<<<dim3(4, WS / 128, WB), 512, 0, stream>>>(
                pbf, vw1t, Pp, 0, (long)WS * WS);
        } else {
            for (int b = 0; b < WB; b++) {
                gemm256_k<<<dim3(WS / 256, WS / 256, 1), 512, 0, stream>>>(
                    hbf, Gt, pbf, WD, WD, WD, WS,
                    (long)WS * WD, (long)WS * WD, 0, b, Lp, rq);
                pv64_k<<<dim3(4, WS / 128, 1), 512, 0, stream>>>(
                    pbf, vw1t, Pp, b, 0);
            }
        }
        // hid = relu(sc_out/l * sum_kp Pp + b1)
        ffh_red<<<WB * WS / 4, 256, 0, stream>>>(Pp, Lp, b1, fhbf, sc_out);
        // ff = hid @ W2 + b2  (f32 into out)
        gemm8_k<5><<<dim3(WD / 128, M / 128, 1), 512, 0, stream>>>(
            fhbf, w2t, b2, out, nullptr, WHID, WHID, WHID, WD, 0, 0, 0, 1.0f, 0);
        // h = LN2(LN1(h + ff))
        ln_k<<<M, 256, 0, stream>>>(h, out, g1, lb1, g2, lb2, hbf,
                                    (l == NLAYER - 1) ? out : nullptr);
    }
}

// Round 10
// 473.614 us; speedup vs baseline: 1.9061x; 1.0644x over previous
//
#include <hip/hip_runtime.h>
#include <hip/hip_bf16.h>
#include <math.h>

#define WB 4
#define WS 2048
#define WD 512
#define WHID 64
#define NLAYER 6

typedef __attribute__((ext_vector_type(8))) short short8;
typedef __attribute__((ext_vector_type(4))) short short4v;
typedef __attribute__((ext_vector_type(4))) float floatx4;
typedef __attribute__((ext_vector_type(16))) float floatx16;

__device__ __forceinline__ short f2bf(float f) {
    union { float f; unsigned u; } x; x.f = f;
    unsigned r = (x.u + 0x7fffu + ((x.u >> 16) & 1u)) >> 16;
    return (short)r;
}

__device__ __forceinline__ float bf2f(short s) {
    union { unsigned u; float f; } c;
    c.u = ((unsigned)(unsigned short)s) << 16;
    return c.f;
}

__device__ __forceinline__ void gl_lds16(const short* g, short* l) {
    __builtin_amdgcn_global_load_lds(
        (const __attribute__((address_space(1))) unsigned*)g,
        (__attribute__((address_space(3))) unsigned*)l, 16, 0, 0);
}

// bijective XCD-aware block swizzle (nwg % 8 == 0): consecutive WORK ids -> same XCD
__device__ __forceinline__ void xcd_swz(int& bx, int& by, int& bz) {
    int gx = gridDim.x, gy = gridDim.y;
    int nwg = gx * gy * gridDim.z;
    int wg = blockIdx.x + gx * (blockIdx.y + gy * blockIdx.z);
    int swz = (wg & 7) * (nwg >> 3) + (wg >> 3);
    bx = swz % gx;
    int t = swz / gx;
    by = t % gy;
    bz = t / gy;
}

__device__ __forceinline__ float block_reduce(float v, bool is_max) {
    __shared__ float tmp[4];
    int lane = threadIdx.x & 63, w = threadIdx.x >> 6;
#pragma unroll
    for (int off = 32; off; off >>= 1) {
        float o = __shfl_xor(v, off);
        v = is_max ? fmaxf(v, o) : v + o;
    }
    __syncthreads();
    if (lane == 0) tmp[w] = v;
    __syncthreads();
    int nw = blockDim.x >> 6;
    float r = tmp[0];
    for (int i = 1; i < nw; i++) r = is_max ? fmaxf(r, tmp[i]) : r + tmp[i];
    return r;
}

// ---------- 256x256 NT GEMM for QK' using 32x32x16 MFMA ----------
// P = exp(h@G + rq) bf16, 32 row-sum partials -> Lp. 8 waves, wave 128x64.
// C layout: col=lane&31 -> 2B/lane stores cover 64B contiguous per row-half.
__global__ __launch_bounds__(512) void gemm256_k(
    const short* __restrict__ A, const short* __restrict__ Bm,
    short* __restrict__ Cb, int K, int lda, int ldb, int ldc,
    long sA, long sB, long sC, int b0, float* __restrict__ Lp,
    const float* __restrict__ rq)
{
    __shared__ __align__(16) short As[2][256 * 64];
    __shared__ __align__(16) short Bs[2][256 * 64];
    int bx, by, bz0;
    xcd_swz(bx, by, bz0);
    int bz = b0 + bz0;
    int tid = threadIdx.x;
    int m0 = by * 256, n0 = bx * 256;
    const short* Ab = A + (long)bz * sA + (long)m0 * lda;
    const short* Bb = Bm + (long)bz * sB + (long)n0 * ldb;
    long coff = (long)bz * sC;

    int lane = tid & 63, w = tid >> 6;
    int l31 = lane & 31, lh = lane >> 5;
    int wm = (w >> 2) * 128, wn = (w & 3) * 64;

    floatx16 acc[4][2];
#pragma unroll
    for (int mi = 0; mi < 4; mi++)
#pragma unroll
        for (int ni = 0; ni < 2; ni++)
#pragma unroll
            for (int r = 0; r < 16; r++) acc[mi][ni][r] = 0.f;

    int sr = tid >> 3;
    int scb = (tid & 7) ^ (sr & 7);
    const short* ga0 = Ab + (long)sr * lda + scb * 8;
    const short* gb0 = Bb + (long)sr * ldb + scb * 8;
    long lda64 = (long)64 * lda, ldb64 = (long)64 * ldb;

    // fragment bases: row = w-tile + frag*32 + (lane&31), k-half = lane>>5
    int aob[4], ax[4], bob[2], bx_[2];
#pragma unroll
    for (int i = 0; i < 4; i++) {
        int ar = wm + i * 32 + l31;
        aob[i] = ar * 64; ax[i] = ar & 7;
    }
#pragma unroll
    for (int i = 0; i < 2; i++) {
        int br = wn + i * 32 + l31;
        bob[i] = br * 64; bx_[i] = br & 7;
    }

    int nt = K >> 6;

    auto stage = [&](int t, int b) {
        const short* ga = ga0 + t * 64;
        const short* gb = gb0 + t * 64;
#pragma unroll
        for (int q = 0; q < 4; q++)
            gl_lds16(ga + (long)q * lda64, &As[b][q * 4096 + tid * 8]);
#pragma unroll
        for (int q = 0; q < 4; q++)
            gl_lds16(gb + (long)q * ldb64, &Bs[b][q * 4096 + tid * 8]);
    };

    stage(0, 0);

    for (int t = 0; t < nt; t++) {
        int cur = t & 1;
        if (t + 1 < nt) {
            stage(t + 1, cur ^ 1);
            asm volatile("s_waitcnt vmcnt(8)" ::: "memory");
        } else {
            asm volatile("s_waitcnt vmcnt(0)" ::: "memory");
        }
        __builtin_amdgcn_s_barrier();
        __builtin_amdgcn_sched_barrier(0);
        const short* as = As[cur];
        const short* bs = Bs[cur];
#pragma unroll
        for (int kk = 0; kk < 4; kk++) {
            short8 av[4], bv[2];
#pragma unroll
            for (int i = 0; i < 4; i++)
                av[i] = *(const short8*)&as[aob[i] + (((2 * kk + lh) ^ ax[i]) * 8)];
#pragma unroll
            for (int i = 0; i < 2; i++)
                bv[i] = *(const short8*)&bs[bob[i] + (((2 * kk + lh) ^ bx_[i]) * 8)];
#pragma unroll
            for (int mi = 0; mi < 4; mi++)
#pragma unroll
                for (int ni = 0; ni < 2; ni++)
                    acc[mi][ni] = __builtin_amdgcn_mfma_f32_32x32x16_bf16(av[mi], bv[ni], acc[mi][ni], 0, 0, 0);
        }
        __builtin_amdgcn_sched_barrier(0);
        __builtin_amdgcn_s_barrier();
    }

    // epilogue: exp, 64B-granular stores, per-wave row sums (64 cols) -> Lp
#pragma unroll
    for (int mi = 0; mi < 4; mi++) {
        float s[16];
#pragma unroll
        for (int r = 0; r < 16; r++) s[r] = 0.f;
#pragma unroll
        for (int ni = 0; ni < 2; ni++) {
            int n = n0 + wn + ni * 32 + l31;
            float rv = rq[(long)bz * WS + n];
#pragma unroll
            for (int r = 0; r < 16; r++) {
                int row = wm + mi * 32 + 4 * lh + (r & 3) + 8 * (r >> 2);
                float e = __expf(acc[mi][ni][r] + rv);
                Cb[coff + (long)(m0 + row) * ldc + n] = f2bf(e);
                s[r] += e;
            }
        }
#pragma unroll
        for (int off = 1; off < 32; off <<= 1)
#pragma unroll
            for (int r = 0; r < 16; r++) s[r] += __shfl_xor(s[r], off);
        if (l31 == 0) {
            long lpb = ((long)bz * 32 + bx * 4 + (w & 3)) * WS + m0 + wm + mi * 32 + 4 * lh;
#pragma unroll
            for (int r = 0; r < 16; r++)
                Lp[lpb + (r & 3) + 8 * (r >> 2)] = s[r];
        }
    }
}

// ---------- 128x128 NT GEMM, 8 waves, BK=64, 2-buf counted-vmcnt ----------
// EPI: 0 = bf16 ((acc+bias)*scale); 5 = f32 (+bias);
//      8 = bf16 transposed within batch: Cb[coff + n*ldc + m], *scale, no bias.
template<int EPI>
__global__ __launch_bounds__(512) void gemm8_k(
    const short* __restrict__ A, const short* __restrict__ Bm,
    const float* __restrict__ bias, float* __restrict__ Cf, short* __restrict__ Cb,
    int K, int lda, int ldb, int ldc,
    long sA, long sB, long sC, float scale, int b0)
{
    __shared__ __align__(16) short As[2][128 * 64];
    __shared__ __align__(16) short Bs[2][128 * 64];
    int bx, by, bz0;
    xcd_swz(bx, by, bz0);
    int tid = threadIdx.x;
    int bz = b0 + bz0;
    int m0 = by * 128, n0 = bx * 128;
    const short* Ab = A + (long)bz * sA + (long)m0 * lda;
    const short* Bb = Bm + (long)bz * sB + (long)n0 * ldb;
    long coff = (long)bz * sC;

    int lane = tid & 63, w = tid >> 6;
    int wm = (w >> 2) * 64, wn = (w & 3) * 32;

    floatx4 acc[4][2];
#pragma unroll
    for (int mi = 0; mi < 4; mi++)
#pragma unroll
        for (int ni = 0; ni < 2; ni++) acc[mi][ni] = (floatx4){0.f, 0.f, 0.f, 0.f};

    int r0 = tid >> 3;
    int sblk = (tid & 7) ^ (r0 & 7);
    const short* ga0 = Ab + (long)r0 * lda + sblk * 8;
    const short* gb0 = Bb + (long)r0 * ldb + sblk * 8;
    long lda64 = (long)64 * lda, ldb64 = (long)64 * ldb;

    int arow = wm + (lane & 15);
    int brow = wn + (lane & 15);
    int a7 = arow & 7, b7 = brow & 7;
    int kb = lane >> 4;
    int aoff0 = arow * 64 + ((kb ^ a7) * 8);
    int aoff1 = arow * 64 + (((kb + 4) ^ a7) * 8);
    int boff0 = brow * 64 + ((kb ^ b7) * 8);
    int boff1 = brow * 64 + (((kb + 4) ^ b7) * 8);

    int nt = K >> 6;

    auto stage = [&](int t, int b) {
        const short* ga = ga0 + t * 64;
        const short* gb = gb0 + t * 64;
        gl_lds16(ga, &As[b][tid * 8]);
        gl_lds16(ga + lda64, &As[b][(tid + 512) * 8]);
        gl_lds16(gb, &Bs[b][tid * 8]);
        gl_lds16(gb + ldb64, &Bs[b][(tid + 512) * 8]);
    };

    stage(0, 0);

    for (int t = 0; t < nt; t++) {
        int cur = t & 1;
        if (t + 1 < nt) {
            stage(t + 1, cur ^ 1);
            asm volatile("s_waitcnt vmcnt(4)" ::: "memory");
        } else {
            asm volatile("s_waitcnt vmcnt(0)" ::: "memory");
        }
        __builtin_amdgcn_s_barrier();
        __builtin_amdgcn_sched_barrier(0);
        const short* as = As[cur];
        const short* bs = Bs[cur];
        short8 av[4], bv[2];
#pragma unroll
        for (int i = 0; i < 4; i++) av[i] = *(const short8*)&as[aoff0 + i * 16 * 64];
#pragma unroll
        for (int i = 0; i < 2; i++) bv[i] = *(const short8*)&bs[boff0 + i * 16 * 64];
#pragma unroll
        for (int mi = 0; mi < 4; mi++)
#pragma unroll
            for (int ni = 0; ni < 2; ni++)
                acc[mi][ni] = __builtin_amdgcn_mfma_f32_16x16x32_bf16(av[mi], bv[ni], acc[mi][ni], 0, 0, 0);
#pragma unroll
        for (int i = 0; i < 4; i++) av[i] = *(const short8*)&as[aoff1 + i * 16 * 64];
#pragma unroll
        for (int i = 0; i < 2; i++) bv[i] = *(const short8*)&bs[boff1 + i * 16 * 64];
#pragma unroll
        for (int mi = 0; mi < 4; mi++)
#pragma unroll
            for (int ni = 0; ni < 2; ni++)
                acc[mi][ni] = __builtin_amdgcn_mfma_f32_16x16x32_bf16(av[mi], bv[ni], acc[mi][ni], 0, 0, 0);
        __builtin_amdgcn_sched_barrier(0);
        __builtin_amdgcn_s_barrier();
    }

    int rl = (lane >> 4) * 4, col = lane & 15;

#pragma unroll
    for (int mi = 0; mi < 4; mi++) {
#pragma unroll
        for (int ni = 0; ni < 2; ni++) {
            int n = n0 + wn + ni * 16 + col;
            if (EPI == 8) {
                int m = m0 + wm + mi * 16 + rl;
                short4v o;
#pragma unroll
                for (int j = 0; j < 4; j++) o[j] = f2bf(acc[mi][ni][j] * scale);
                *(short4v*)&Cb[coff + (long)n * ldc + m] = o;
            } else {
                float bvv = bias ? bias[n] : 0.f;
#pragma unroll
                for (int j = 0; j < 4; j++) {
                    int r = wm + mi * 16 + rl + j;
                    float v = (acc[mi][ni][j] + bvv) * scale;
                    if (EPI == 5) Cf[coff + (long)(m0 + r) * ldc + n] = v;
                    else Cb[coff + (long)(m0 + r) * ldc + n] = f2bf(v);
                }
            }
        }
    }
}

// ---------- PV' split-K: partial[kp] = P[:,kp*512:+512] @ VW1t^T, f32 ----------
__global__ __launch_bounds__(512) void pv64_k(
    const short* __restrict__ P, const short* __restrict__ Vw,
    float* __restrict__ Pp, int b0, long sP)
{
    __shared__ __align__(16) short As[2][128 * 64];
    __shared__ __align__(16) short Bs[2][64 * 64];
    int kp = blockIdx.x, my = blockIdx.y;
    int bz = b0 + blockIdx.z;
    int tid = threadIdx.x;
    int m0 = my * 128;
    const short* Ab = P + (long)bz * sP + (long)m0 * WS + kp * 512;
    const short* Bb = Vw + (long)bz * WHID * WS + kp * 512;

    int lane = tid & 63, w = tid >> 6;
    int wm = (w >> 1) * 32, wn = (w & 1) * 32;

    floatx4 acc[2][2];
#pragma unroll
    for (int mi = 0; mi < 2; mi++)
#pragma unroll
        for (int ni = 0; ni < 2; ni++) acc[mi][ni] = (floatx4){0.f, 0.f, 0.f, 0.f};

    int sr = tid >> 3;
    int scb = (tid & 7) ^ (sr & 7);
    const short* ga0 = Ab + (long)sr * WS + scb * 8;
    const short* gb0 = Bb + (long)sr * WS + scb * 8;
    long lda64 = (long)64 * WS;

    int arow = wm + (lane & 15);
    int brow = wn + (lane & 15);
    int a7 = arow & 7, b7 = brow & 7;
    int kb = lane >> 4;
    int aoff0 = arow * 64 + ((kb ^ a7) * 8);
    int aoff1 = arow * 64 + (((kb + 4) ^ a7) * 8);
    int boff0 = brow * 64 + ((kb ^ b7) * 8);
    int boff1 = brow * 64 + (((kb + 4) ^ b7) * 8);

    auto stage = [&](int t, int b) {
        const short* ga = ga0 + t * 64;
        gl_lds16(ga, &As[b][tid * 8]);
        gl_lds16(ga + lda64, &As[b][(tid + 512) * 8]);
        gl_lds16(gb0 + t * 64, &Bs[b][tid * 8]);
    };

    stage(0, 0);

    for (int t = 0; t < 8; t++) {
        int cur = t & 1;
        if (t + 1 < 8) {
            stage(t + 1, cur ^ 1);
            asm volatile("s_waitcnt vmcnt(3)" ::: "memory");
        } else {
            asm volatile("s_waitcnt vmcnt(0)" ::: "memory");
        }
        __builtin_amdgcn_s_barrier();
        __builtin_amdgcn_sched_barrier(0);
        const short* as = As[cur];
        const short* bs = Bs[cur];
        short8 av[2], bv[2];
#pragma unroll
        for (int i = 0; i < 2; i++) av[i] = *(const short8*)&as[aoff0 + i * 1024];
#pragma unroll
        for (int i = 0; i < 2; i++) bv[i] = *(const short8*)&bs[boff0 + i * 1024];
#pragma unroll
        for (int mi = 0; mi < 2; mi++)
#pragma unroll
            for (int ni = 0; ni < 2; ni++)
                acc[mi][ni] = __builtin_amdgcn_mfma_f32_16x16x32_bf16(av[mi], bv[ni], acc[mi][ni], 0, 0, 0);
#pragma unroll
        for (int i = 0; i < 2; i++) av[i] = *(const short8*)&as[aoff1 + i * 1024];
#pragma unroll
        for (int i = 0; i < 2; i++) bv[i] = *(const short8*)&bs[boff1 + i * 1024];
#pragma unroll
        for (int mi = 0; mi < 2; mi++)
#pragma unroll
            for (int ni = 0; ni < 2; ni++)
                acc[mi][ni] = __builtin_amdgcn_mfma_f32_16x16x32_bf16(av[mi], bv[ni], acc[mi][ni], 0, 0, 0);
        __builtin_amdgcn_sched_barrier(0);
        __builtin_amdgcn_s_barrier();
    }

    int rl = (lane >> 4) * 4, col = lane & 15;
#pragma unroll
    for (int mi = 0; mi < 2; mi++) {
#pragma unroll
        for (int ni = 0; ni < 2; ni++) {
            int jn = wn + ni * 16 + col;
#pragma unroll
            for (int j = 0; j < 4; j++) {
                int m = m0 + wm + mi * 16 + rl + j;
                Pp[(((long)kp * WB + bz) * WS + m) * WHID + jn] = acc[mi][ni][j];
            }
        }
    }
}

// reduce: hid = relu(sc_out/l * sum_kp Pp + b1) -> fhbf bf16
__global__ __launch_bounds__(256) void ffh_red(
    const float* __restrict__ Pp, const float* __restrict__ Lp,
    const float* __restrict__ b1, short* __restrict__ fhbf, float sc)
{
    int idx = blockIdx.x * 4 + (threadIdx.x >> 6);  // row over B*S
    int j = threadIdx.x & 63;
    int b = idx >> 11, m = idx & (WS - 1);
    float l = 0.f;
    const float* lp = Lp + (long)b * 32 * WS + m;
#pragma unroll 8
    for (int p2 = 0; p2 < 32; p2++) l += lp[(long)p2 * WS];
    float s = 0.f;
#pragma unroll
    for (int kp = 0; kp < 4; kp++)
        s += Pp[(((long)kp * WB + b) * WS + m) * WHID + j];
    float v = fmaxf(s * (sc / l) + b1[j], 0.f);
    fhbf[(long)idx * WHID + j] = f2bf(v);
}

// rq[b][n] = sc_attn * dot(bq, k[b][n])
__global__ __launch_bounds__(256) void rq_k(const short* __restrict__ kbf,
                                            const float* __restrict__ bq,
                                            float* __restrict__ rq)
{
    __shared__ float sbq[WD];
    int tid = threadIdx.x;
    for (int i = tid; i < WD; i += 256) sbq[i] = bq[i];
    __syncthreads();
    int idx = blockIdx.x * 256 + tid;
    const short* kr = kbf + (long)idx * WD;
    float s = 0.f;
    for (int d = 0; d < WD; d += 8) {
        short8 kv = *(const short8*)(kr + d);
#pragma unroll
        for (int e = 0; e < 8; e++) s += bf2f(kv[e]) * sbq[d + e];
    }
    rq[idx] = s * 0.125f;
}

// ---------------- 64-tile GEMM (M<=64): C = A@B^T * scale, bf16 out ----------------
__global__ __launch_bounds__(256) void gemm_k(
    const short* __restrict__ A, const short* __restrict__ Bm,
    short* __restrict__ Cb,
    int M, int N, int K, int lda, int ldb, int ldc,
    long sA, long sB, long sC, float scale, int b0)
{
    __shared__ short As[64][40];
    __shared__ short Bs[64][40];
    int bx, by, bz0;
    xcd_swz(bx, by, bz0);
    int tid = threadIdx.x;
    int bz = b0 + bz0;
    const short* Ab = A + (long)bz * sA;
    const short* Bb = Bm + (long)bz * sB;
    long coff = (long)bz * sC;
    int m0 = by * 64, n0 = bx * 64;

    floatx4 acc[4];
#pragma unroll
    for (int c = 0; c < 4; c++) acc[c] = (floatx4){0.f, 0.f, 0.f, 0.f};

    int lane = tid & 63, w = tid >> 6;
    int arow = w * 16 + (lane & 15);
    int koff = (lane >> 4) * 8;

    for (int kt = 0; kt < K; kt += 32) {
        {
            int r = tid >> 2, kc = (tid & 3) * 8;
            int ar = m0 + r < M ? m0 + r : M - 1;
            short8 av = *(const short8*)(Ab + (long)ar * lda + kt + kc);
            *(short8*)&As[r][kc] = av;
        }
        {
            int r = tid >> 2, kc = (tid & 3) * 8;
            short8 bv = *(const short8*)(Bb + (long)(n0 + r) * ldb + kt + kc);
            *(short8*)&Bs[r][kc] = bv;
        }
        __syncthreads();
        short8 a = *(const short8*)&As[arow][koff];
#pragma unroll
        for (int c = 0; c < 4; c++) {
            short8 b = *(const short8*)&Bs[c * 16 + (lane & 15)][koff];
            acc[c] = __builtin_amdgcn_mfma_f32_16x16x32_bf16(a, b, acc[c], 0, 0, 0);
        }
        __syncthreads();
    }

    int rl = (lane >> 4) * 4, col = lane & 15;
    int mb = m0 + w * 16 + rl;
#pragma unroll
    for (int c = 0; c < 4; c++) {
        int n = n0 + c * 16 + col;
#pragma unroll
        for (int j = 0; j < 4; j++) {
            int m = mb + j;
            if (m < M) Cb[coff + (long)m * ldc + n] = f2bf(acc[c][j] * scale);
        }
    }
}

__global__ __launch_bounds__(256) void ln_k(float* __restrict__ h,
                                            const short* __restrict__ ff,
                                            const float* __restrict__ g1, const float* __restrict__ bb1,
                                            const float* __restrict__ g2, const float* __restrict__ bb2,
                                            short* __restrict__ hbf,
                                            float* __restrict__ outp)
{
    long r = blockIdx.x;
    int i = threadIdx.x;
    float2 hv = *(const float2*)&h[r * WD + i * 2];
    const short* fp = &ff[r * WD + i * 2];
    float a = hv.x + bf2f(fp[0]), b = hv.y + bf2f(fp[1]);
    float mu = block_reduce(a + b, false) * (1.f / WD);
    float da = a - mu, db = b - mu;
    float var = block_reduce(da * da + db * db, false) * (1.f / WD);
    float rs = rsqrtf(var + 1e-5f);
    float y0 = da * rs * g1[2 * i] + bb1[2 * i];
    float y1 = db * rs * g1[2 * i + 1] + bb1[2 * i + 1];
    float mu2 = block_reduce(y0 + y1, false) * (1.f / WD);
    float d0 = y0 - mu2, d1 = y1 - mu2;
    float var2 = block_reduce(d0 * d0 + d1 * d1, false) * (1.f / WD);
    float rs2 = rsqrtf(var2 + 1e-5f);
    float z0 = d0 * rs2 * g2[2 * i] + bb2[2 * i];
    float z1 = d1 * rs2 * g2[2 * i + 1] + bb2[2 * i + 1];
    *(float2*)&h[r * WD + i * 2] = make_float2(z0, z1);
    hbf[r * WD + i * 2] = f2bf(z0);
    hbf[r * WD + i * 2 + 1] = f2bf(z1);
    if (outp) *(float2*)&outp[r * WD + i * 2] = make_float2(z0, z1);
}

__global__ void conv_x_k(const float* __restrict__ x, float* __restrict__ h,
                         short* __restrict__ hbf, int n4)
{
    int i = blockIdx.x * blockDim.x + threadIdx.x;
    for (; i < n4; i += gridDim.x * blockDim.x) {
        float4 v = ((const float4*)x)[i];
        ((float4*)h)[i] = v;
        short4v o;
        o[0] = f2bf(v.x); o[1] = f2bf(v.y); o[2] = f2bf(v.z); o[3] = f2bf(v.w);
        *(short4v*)&hbf[i * 4] = o;
    }
}

__global__ void conv_w_k(const float* __restrict__ x, short* __restrict__ w, int n4)
{
    int i = blockIdx.x * blockDim.x + threadIdx.x;
    for (; i < n4; i += gridDim.x * blockDim.x) {
        float4 v = ((const float4*)x)[i];
        short4v o;
        o[0] = f2bf(v.x); o[1] = f2bf(v.y); o[2] = f2bf(v.z); o[3] = f2bf(v.w);
        *(short4v*)&w[i * 4] = o;
    }
}

// W [R][C] f32 -> Wt [C][R] bf16
__global__ __launch_bounds__(256) void transpose_w_k(const float* __restrict__ W,
                                                     short* __restrict__ Wt, int R, int C)
{
    __shared__ short t[32][33];
    int c0 = blockIdx.x * 32, r0 = blockIdx.y * 32;
    int tx = threadIdx.x & 31, ty = threadIdx.x >> 5;
#pragma unroll
    for (int i = 0; i < 32; i += 8)
        t[ty + i][tx] = f2bf(W[(long)(r0 + ty + i) * C + c0 + tx]);
    __syncthreads();
#pragma unroll
    for (int i = 0; i < 32; i += 8)
        Wt[(long)(c0 + ty + i) * R + r0 + tx] = t[tx][ty + i];
}

extern "C" void kernel_launch(void* const* d_in, const int* in_sizes, int n_in,
                              void* d_out, int out_size, void* d_ws, size_t ws_size,
                              hipStream_t stream)
{
    const float* x   = (const float*)d_in[0];
    const float* Wq  = (const float*)d_in[1];
    const float* bq  = (const float*)d_in[2];
    const float* Wk  = (const float*)d_in[3];
    const float* bk  = (const float*)d_in[4];
    const float* Wv  = (const float*)d_in[5];
    const float* bv  = (const float*)d_in[6];
    const float* W1  = (const float*)d_in[7];
    const float* b1  = (const float*)d_in[8];
    const float* W2  = (const float*)d_in[9];
    const float* b2  = (const float*)d_in[10];
    const float* g1  = (const float*)d_in[11];
    const float* lb1 = (const float*)d_in[12];
    const float* g2  = (const float*)d_in[13];
    const float* lb2 = (const float*)d_in[14];
    float* out = (float*)d_out;

    char* p = (char*)d_ws;
    auto carve = [&](size_t bytes) -> char* {
        char* r = p;
        p += (bytes + 255) & ~(size_t)255;
        return r;
    };
    float* h    = (float*)carve((size_t)WB * WS * WD * 4);
    short* hbf  = (short*)carve((size_t)WB * WS * WD * 2);
    short* kbf  = (short*)carve((size_t)WB * WS * WD * 2);
    short* vbf  = (short*)carve((size_t)WB * WS * WD * 2);
    short* Gt   = (short*)carve((size_t)WB * WS * WD * 2);   // [b][n][e]
    short* vw1t = (short*)carve((size_t)WB * WHID * WS * 2); // [b][j][s]
    short* fhbf = (short*)carve((size_t)WB * WS * WHID * 2);
    short* ffb  = (short*)carve((size_t)WB * WS * WD * 2);   // bf16 ff
    short* wqb  = (short*)carve((size_t)WD * WD * 2);
    short* wkt  = (short*)carve((size_t)WD * WD * 2);
    short* wvt  = (short*)carve((size_t)WD * WD * 2);
    short* w1t  = (short*)carve((size_t)WHID * WD * 2);      // [64][512]
    short* w2t  = (short*)carve((size_t)WD * WHID * 2);      // [512][64]
    float* rq   = (float*)carve((size_t)WB * WS * 4);
    float* Lp   = (float*)carve((size_t)WB * 32 * WS * 4);
    float* Pp   = (float*)carve((size_t)4 * WB * WS * WHID * 4);
    size_t used_base = (size_t)(p - (char*)d_ws);
    size_t full_extra = (size_t)WB * WS * WS * 2 + 1024;
    bool full = ws_size >= used_base + full_extra;
    short* pbf;
    if (full) pbf = (short*)carve((size_t)WB * WS * WS * 2);
    else      pbf = (short*)carve((size_t)WS * WS * 2);

    const int M = WB * WS;
    const float sc_attn = 0.125f;
    const float sc_out  = 0.04419417382f;   // 1/sqrt(512)

    conv_x_k<<<2048, 256, 0, stream>>>(x, h, hbf, WB * WS * WD / 4);
    conv_w_k<<<256, 256, 0, stream>>>(Wq, wqb, WD * WD / 4);
    transpose_w_k<<<dim3(WD / 32, WD / 32), 256, 0, stream>>>(Wk, wkt, WD, WD);
    transpose_w_k<<<dim3(WD / 32, WD / 32), 256, 0, stream>>>(Wv, wvt, WD, WD);
    transpose_w_k<<<dim3(WHID / 32, WD / 32), 256, 0, stream>>>(W1, w1t, WD, WHID);
    transpose_w_k<<<dim3(WD / 32, WHID / 32), 256, 0, stream>>>(W2, w2t, WHID, WD);

    // k = x @ Wk + bk ; v = x @ Wv + bv   (bf16 row-major [B*S][D])
    gemm8_k<0><<<dim3(WD / 128, M / 128, 1), 512, 0, stream>>>(
        hbf, wkt, bk, nullptr, kbf, WD, WD, WD, WD, 0, 0, 0, 1.0f, 0);
    gemm8_k<0><<<dim3(WD / 128, M / 128, 1), 512, 0, stream>>>(
        hbf, wvt, bv, nullptr, vbf, WD, WD, WD, WD, 0, 0, 0, 1.0f, 0);

    // Gt[b][n][e] = sc_attn * sum_d Wq[e][d]*k[b][n][d]
    gemm8_k<8><<<dim3(WS / 128, WD / 128, WB), 512, 0, stream>>>(
        wqb, kbf, nullptr, nullptr, Gt, WD, WD, WD, WD,
        0, (long)WS * WD, (long)WS * WD, sc_attn, 0);
    // rq[b][n] = sc_attn * dot(bq, k[b][n])
    rq_k<<<WB * WS / 256, 256, 0, stream>>>(kbf, bq, rq);
    // vw1t[b][j][s] = sum_d W1[d][j]*v[b][s][d]
    gemm_k<<<dim3(WS / 64, 1, WB), 256, 0, stream>>>(
        w1t, vbf, vw1t, WHID, WS, WD, WD, WD, WS,
        0, (long)WS * WD, (long)WHID * WS, 1.0f, 0);

    for (int l = 0; l < NLAYER; l++) {
        if (full) {
            gemm256_k<<<dim3(WS / 256, WS / 256, WB), 512, 0, stream>>>(
                hbf, Gt, pbf, WD, WD, WD, WS,
                (long)WS * WD, (long)WS * WD, (long)WS * WS, 0, Lp, rq);
            pv64_k<<<dim3(4, WS / 128, WB), 512, 0, stream>>>(
                pbf, vw1t, Pp, 0, (long)WS * WS);
        } else {
            for (int b = 0; b < WB; b++) {
                gemm256_k<<<dim3(WS / 256, WS / 256, 1), 512, 0, stream>>>(
                    hbf, Gt, pbf, WD, WD, WD, WS,
                    (long)WS * WD, (long)WS * WD, 0, b, Lp, rq);
                pv64_k<<<dim3(4, WS / 128, 1), 512, 0, stream>>>(
                    pbf, vw1t, Pp, b, 0);
            }
        }
        // hid = relu(sc_out/l * sum_kp Pp + b1)
        ffh_red<<<WB * WS / 4, 256, 0, stream>>>(Pp, Lp, b1, fhbf, sc_out);
        // ff = hid @ W2 + b2  (bf16 into ffb)
        gemm8_k<0><<<dim3(WD / 128, M / 128, 1), 512, 0, stream>>>(
            fhbf, w2t, b2, nullptr, ffb, WHID, WHID, WHID, WD, 0, 0, 0, 1.0f, 0);
        // h = LN2(LN1(h + ff))
        ln_k<<<M, 256, 0, stream>>>(h, ffb, g1, lb1, g2, lb2, hbf,
                                    (l == NLAYER - 1) ? out : nullptr);
    }
}